// Round 1
// baseline (586.172 us; speedup 1.0000x reference)
//
#include <hip/hip_runtime.h>
#include <hip/hip_bf16.h>

// Dims
#define B_  16
#define T_  256
#define C_  64
#define F_  128
#define O_  32   // GO
#define H_  32
#define G4_ 128  // 4*H

// ---------------------------------------------------------------------------
// K0: softmax of spectral_w rows (64 rows of 128)
// ---------------------------------------------------------------------------
__global__ __launch_bounds__(64) void k_sw(const float* __restrict__ w,
                                           float* __restrict__ sw) {
    int c = blockIdx.x, lane = threadIdx.x;
    const float* row = w + c * F_;
    float v0 = row[lane], v1 = row[lane + 64];
    float m = fmaxf(v0, v1);
#pragma unroll
    for (int s = 1; s < 64; s <<= 1) m = fmaxf(m, __shfl_xor(m, s));
    float e0 = __expf(v0 - m), e1 = __expf(v1 - m);
    float s = e0 + e1;
#pragma unroll
    for (int s_ = 1; s_ < 64; s_ <<= 1) s += __shfl_xor(s, s_);
    sw[c * F_ + lane] = e0 / s;
    sw[c * F_ + lane + 64] = e1 / s;
}

// ---------------------------------------------------------------------------
// K1: fused scale + normalize + A-accumulate + Wh + s1/s2
// grid (B, T/TC), block 256.  TC=4.
// ---------------------------------------------------------------------------
#define TC 4
#define XS_STRIDE 132

__global__ __launch_bounds__(256) void k_phase1(
    const float* __restrict__ x, const float* __restrict__ sw,
    const float* __restrict__ gat_W, const float* __restrict__ gat_a,
    float* __restrict__ A, float* __restrict__ Wh,
    float* __restrict__ s1, float* __restrict__ s2) {
    const int b = blockIdx.x;
    const int tc = blockIdx.y;
    const int tid = threadIdx.x;

    __shared__ float xs[C_ * XS_STRIDE];
    __shared__ float Wl[F_ * O_];
    __shared__ float invn[C_];

    // preload sw slice this thread scales (same elements every t)
    float4 swr[8];
    const float4* sw4 = (const float4*)sw;
#pragma unroll
    for (int i = 0; i < 8; i++) swr[i] = sw4[tid + 256 * i];

    // gat_W -> LDS (natural [128][32])
    {
        const float4* w4 = (const float4*)gat_W;
        float4* wl4 = (float4*)Wl;
        for (int i = tid; i < 1024; i += 256) wl4[i] = w4[i];
    }
    // gat_a slices for this thread's 8 o's
    const int og = (tid & 3) * 8;
    float ga1[8], ga2[8];
#pragma unroll
    for (int i = 0; i < 8; i++) {
        ga1[i] = gat_a[og + i];
        ga2[i] = gat_a[O_ + og + i];
    }

    float acc[16];
#pragma unroll
    for (int i = 0; i < 16; i++) acc[i] = 0.f;

    const int ty = tid >> 4;   // 0..15  (c = ty + 16*i)
    const int tx = tid & 15;   // 0..15  (d = tx + 16*j)
    const int wc = tid >> 2;   // Wh row for this quad

    for (int tt = 0; tt < TC; ++tt) {
        const int t = tc * TC + tt;
        const float4* xg = (const float4*)(x + ((size_t)(b * T_ + t)) * (C_ * F_));
        __syncthreads();  // protect xs against previous iteration readers
#pragma unroll
        for (int i = 0; i < 8; i++) {
            int e4 = tid + 256 * i;    // float4 index
            int c = e4 >> 5;           // row
            int f4 = e4 & 31;          // float4 col
            float4 v = xg[e4];
            float4 s = swr[i];
            v.x *= s.x; v.y *= s.y; v.z *= s.z; v.w *= s.w;
            *((float4*)&xs[c * XS_STRIDE + 4 * f4]) = v;
        }
        __syncthreads();
        // row norms (unscaled-by-norm xs)
        if (tid < C_) {
            float ss = 0.f;
            const float* row = &xs[tid * XS_STRIDE];
#pragma unroll 4
            for (int f = 0; f < F_; f++) { float v = row[f]; ss += v * v; }
            invn[tid] = 1.0f / (sqrtf(ss) + 1e-8f);
        }
        // Wh = xs @ gat_W  (8 outputs per thread) + s1/s2
        {
            float wacc[8];
#pragma unroll
            for (int i = 0; i < 8; i++) wacc[i] = 0.f;
            const float* row = &xs[wc * XS_STRIDE];
            for (int k = 0; k < F_; k += 4) {
                float4 xv = *(const float4*)&row[k];
#pragma unroll
                for (int kk = 0; kk < 4; kk++) {
                    float xvk = (kk == 0) ? xv.x : (kk == 1) ? xv.y : (kk == 2) ? xv.z : xv.w;
                    const float* wrow = &Wl[(k + kk) * O_ + og];
#pragma unroll
                    for (int i = 0; i < 8; i++) wacc[i] += xvk * wrow[i];
                }
            }
            float* wout = Wh + ((size_t)(b * T_ + t)) * (C_ * O_) + wc * O_ + og;
#pragma unroll
            for (int i = 0; i < 8; i++) wout[i] = wacc[i];
            float p1 = 0.f, p2 = 0.f;
#pragma unroll
            for (int i = 0; i < 8; i++) { p1 += wacc[i] * ga1[i]; p2 += wacc[i] * ga2[i]; }
            p1 += __shfl_xor(p1, 1); p1 += __shfl_xor(p1, 2);
            p2 += __shfl_xor(p2, 1); p2 += __shfl_xor(p2, 2);
            if ((tid & 3) == 0) {
                s1[(b * T_ + t) * C_ + wc] = p1;
                s2[(b * T_ + t) * C_ + wc] = p2;
            }
        }
        __syncthreads();  // invn ready; all xs readers done
        // scale xs in place by invn (now xs = Hn)
#pragma unroll
        for (int i = 0; i < 8; i++) {
            int e4 = tid + 256 * i;
            int c = e4 >> 5;
            int f4 = e4 & 31;
            float inv = invn[c];
            float4* p = (float4*)&xs[c * XS_STRIDE + 4 * f4];
            float4 v = *p;
            v.x *= inv; v.y *= inv; v.z *= inv; v.w *= inv;
            *p = v;
        }
        __syncthreads();
        // A accumulation: 4x4 register tile, c = ty+16i, d = tx+16j
        for (int k = 0; k < F_; k += 4) {
            float4 ar[4], br[4];
#pragma unroll
            for (int i = 0; i < 4; i++) ar[i] = *(const float4*)&xs[(ty + 16 * i) * XS_STRIDE + k];
#pragma unroll
            for (int j = 0; j < 4; j++) br[j] = *(const float4*)&xs[(tx + 16 * j) * XS_STRIDE + k];
#pragma unroll
            for (int i = 0; i < 4; i++)
#pragma unroll
                for (int j = 0; j < 4; j++)
                    acc[i * 4 + j] += ar[i].x * br[j].x + ar[i].y * br[j].y +
                                      ar[i].z * br[j].z + ar[i].w * br[j].w;
        }
    }
#pragma unroll
    for (int i = 0; i < 4; i++)
#pragma unroll
        for (int j = 0; j < 4; j++)
            atomicAdd(&A[b * (C_ * C_) + (ty + 16 * i) * C_ + (tx + 16 * j)], acc[i * 4 + j]);
}

// ---------------------------------------------------------------------------
// K2: top-4 selection + mask symmetrize -> amask bitmask per (b,c)
// grid B, block 64
// ---------------------------------------------------------------------------
__global__ __launch_bounds__(64) void k_topk(const float* __restrict__ A,
                                             unsigned long long* __restrict__ amask) {
    int b = blockIdx.x;
    int c = threadIdx.x;
    __shared__ unsigned long long tk[C_];
    const float* row = A + b * (C_ * C_) + c * C_;
    unsigned long long sel = 0ULL;
    for (int r = 0; r < 4; r++) {
        float best = -1e30f;
        int bi = 0;
        for (int d = 0; d < C_; d++) {
            if (sel & (1ULL << d)) continue;
            float v = row[d];
            if (v > best) { best = v; bi = d; }
        }
        sel |= (1ULL << bi);
    }
    unsigned long long t = sel & ~(1ULL << c);  // drop diagonal
    tk[c] = t;
    __syncthreads();
    unsigned long long sym = t;
    for (int d = 0; d < C_; d++)
        if ((tk[d] >> c) & 1ULL) sym |= (1ULL << d);
    // amask = (sym & (A>0)) | eye
    unsigned long long m = (1ULL << c);
    unsigned long long s2 = sym;
    while (s2) {
        int d = __ffsll(s2) - 1;
        s2 &= s2 - 1;
        if (row[d] > 0.f) m |= (1ULL << d);
    }
    amask[b * C_ + c] = m;
}

// ---------------------------------------------------------------------------
// K3: GAT attention + relu + pooling -> hpool (B,T,32)
// grid B*T, block 64 (thread = row c)
// ---------------------------------------------------------------------------
__global__ __launch_bounds__(64) void k_gat(
    const float* __restrict__ Wh, const float* __restrict__ s1,
    const float* __restrict__ s2, const unsigned long long* __restrict__ amask,
    const float* __restrict__ pool_w, const float* __restrict__ pool_b,
    float* __restrict__ hout) {
    int bt = blockIdx.x;
    int b = bt >> 8;
    int c = threadIdx.x;
    __shared__ float whs[C_ * 33];
    __shared__ float s2s[C_];
    __shared__ float buf[C_ * 33];

    const float* wg = Wh + (size_t)bt * (C_ * O_);
    for (int i = c; i < C_ * O_; i += 64)
        whs[(i >> 5) * 33 + (i & 31)] = wg[i];
    s2s[c] = s2[bt * C_ + c];
    float s1c = s1[bt * C_ + c];
    unsigned long long m = amask[b * C_ + c];
    __syncthreads();

    // masked softmax over set bits only (others exp()->0 exactly)
    float mx = -1e30f;
    unsigned long long mm = m;
    while (mm) {
        int d = __ffsll(mm) - 1; mm &= mm - 1;
        float v = s1c + s2s[d];
        v = v > 0.f ? v : 0.2f * v;
        mx = fmaxf(mx, v);
    }
    float ssum = 0.f;
    mm = m;
    while (mm) {
        int d = __ffsll(mm) - 1; mm &= mm - 1;
        float v = s1c + s2s[d];
        v = v > 0.f ? v : 0.2f * v;
        ssum += __expf(v - mx);
    }
    float inv = 1.0f / ssum;
    float g[O_];
#pragma unroll
    for (int i = 0; i < O_; i++) g[i] = 0.f;
    mm = m;
    while (mm) {
        int d = __ffsll(mm) - 1; mm &= mm - 1;
        float v = s1c + s2s[d];
        v = v > 0.f ? v : 0.2f * v;
        float a = __expf(v - mx);
        const float* wr = &whs[d * 33];
#pragma unroll
        for (int i = 0; i < O_; i++) g[i] += a * wr[i];
    }
    float lg = pool_b[0];
#pragma unroll
    for (int i = 0; i < O_; i++) {
        g[i] = fmaxf(g[i] * inv, 0.f);   // relu(gat)
        lg += g[i] * pool_w[i];
    }
    // softmax over c (full wave)
    float wmx = lg;
#pragma unroll
    for (int s = 1; s < 64; s <<= 1) wmx = fmaxf(wmx, __shfl_xor(wmx, s));
    float we = __expf(lg - wmx);
    float wsum = we;
#pragma unroll
    for (int s = 1; s < 64; s <<= 1) wsum += __shfl_xor(wsum, s);
    float wcf = we / wsum;
#pragma unroll
    for (int i = 0; i < O_; i++) buf[c * 33 + i] = g[i] * wcf;
    __syncthreads();
    if (c < O_) {
        float h = 0.f;
        for (int d = 0; d < C_; d++) h += buf[d * 33 + c];
        hout[bt * O_ + c] = h;
    }
}

// ---------------------------------------------------------------------------
// K4a: LSTM input projection gx = h @ Wi + b (both dirs, parallel over t)
// grid 2*B*T, block 128
// ---------------------------------------------------------------------------
__global__ __launch_bounds__(128) void k_lstm_pre(
    const float* __restrict__ hin,
    const float* __restrict__ Wi_f, const float* __restrict__ b_f,
    const float* __restrict__ Wi_r, const float* __restrict__ b_r,
    float* __restrict__ gx) {
    int id = blockIdx.x;
    int dir = id >> 12;
    int bt = id & 4095;
    const float* Wi = dir ? Wi_r : Wi_f;
    const float* bb = dir ? b_r : b_f;
    int g = threadIdx.x;
    __shared__ float hs[H_];
    if (g < H_) hs[g] = hin[bt * O_ + g];
    __syncthreads();
    float acc = bb[g];
#pragma unroll
    for (int k = 0; k < H_; k++) acc += hs[k] * Wi[k * G4_ + g];
    gx[((size_t)dir * 4096 + bt) * G4_ + g] = acc;
}

// ---------------------------------------------------------------------------
// K4b: sequential LSTM recurrence. grid 2*B (dir,b), block 128.
// ---------------------------------------------------------------------------
__global__ __launch_bounds__(128) void k_lstm_seq(
    const float* __restrict__ gx,
    const float* __restrict__ Whf, const float* __restrict__ Whr,
    float* __restrict__ hcat) {
    int dir = blockIdx.x & 1;
    int b = blockIdx.x >> 1;
    int tid = threadIdx.x;
    __shared__ float wl[H_ * G4_];
    __shared__ float hprev[H_];
    __shared__ float gbuf[G4_];
    const float* W = dir ? Whr : Whf;
    for (int i = tid; i < H_ * G4_; i += 128) wl[i] = W[i];
    if (tid < H_) hprev[tid] = 0.f;
    float cst = 0.f;
    const float* gxb = gx + ((size_t)dir * 4096 + b * T_) * G4_;
    __syncthreads();
    float nxt = gxb[(dir ? (T_ - 1) : 0) * G4_ + tid];
    for (int s = 0; s < T_; s++) {
        int t = dir ? (T_ - 1 - s) : s;
        float cur = nxt;
        if (s < T_ - 1) {
            int t2 = dir ? (T_ - 2 - s) : (s + 1);
            nxt = gxb[t2 * G4_ + tid];
        }
        float acc = cur;
#pragma unroll
        for (int k = 0; k < H_; k++) acc += hprev[k] * wl[k * G4_ + tid];
        gbuf[tid] = acc;
        __syncthreads();
        if (tid < H_) {
            float iv = gbuf[tid], fv = gbuf[tid + 32], gv = gbuf[tid + 64], ov = gbuf[tid + 96];
            float si = 1.f / (1.f + __expf(-iv));
            float sf = 1.f / (1.f + __expf(-fv));
            float so = 1.f / (1.f + __expf(-ov));
            cst = sf * cst + si * tanhf(gv);
            float h = so * tanhf(cst);
            hprev[tid] = h;
            hcat[((size_t)b * T_ + t) * (2 * H_) + dir * H_ + tid] = h;
        }
        __syncthreads();
    }
}

// ---------------------------------------------------------------------------
// K5: temporal attention + LN + fc1 + fc2 -> out (B,3). grid B, block 256.
// ---------------------------------------------------------------------------
__global__ __launch_bounds__(256) void k_final(
    const float* __restrict__ hcat,
    const float* __restrict__ taW, const float* __restrict__ tab,
    const float* __restrict__ tav,
    const float* __restrict__ lng, const float* __restrict__ lnb,
    const float* __restrict__ w1, const float* __restrict__ b1,
    const float* __restrict__ w2, const float* __restrict__ b2,
    float* __restrict__ out) {
    int b = blockIdx.x;
    int t = threadIdx.x;
    __shared__ float Wl[64 * 64];
    __shared__ float al[T_];
    __shared__ float wred[4];
    __shared__ float ctx[64];
    __shared__ float a1[32];
    for (int i = t; i < 4096; i += 256) Wl[i] = taW[i];
    float4 hr[16];
    const float4* hb = (const float4*)(hcat + ((size_t)b * T_ + t) * 64);
#pragma unroll
    for (int i = 0; i < 16; i++) hr[i] = hb[i];
    __syncthreads();
    float sc = 0.f;
    for (int j = 0; j < 64; j++) {
        float s = tab[j];
#pragma unroll
        for (int k4 = 0; k4 < 16; k4++) {
            float4 h4 = hr[k4];
            const float* wcol = &Wl[(4 * k4) * 64 + j];
            s += h4.x * wcol[0] + h4.y * wcol[64] + h4.z * wcol[128] + h4.w * wcol[192];
        }
        sc += tanhf(s) * tav[j];
    }
    sc *= (1.0f / 1.5f);
    // block softmax over 256 t's
    int wave = t >> 6, lane = t & 63;
    float m = sc;
#pragma unroll
    for (int s_ = 1; s_ < 64; s_ <<= 1) m = fmaxf(m, __shfl_xor(m, s_));
    if (lane == 0) wred[wave] = m;
    __syncthreads();
    m = fmaxf(fmaxf(wred[0], wred[1]), fmaxf(wred[2], wred[3]));
    float e = __expf(sc - m);
    float ssum = e;
#pragma unroll
    for (int s_ = 1; s_ < 64; s_ <<= 1) ssum += __shfl_xor(ssum, s_);
    __syncthreads();
    if (lane == 0) wred[wave] = ssum;
    __syncthreads();
    float S = wred[0] + wred[1] + wred[2] + wred[3];
    al[t] = e / S;
    __syncthreads();
    // ctx + LN by wave 0
    if (t < 64) {
        float ctxo = 0.f;
        for (int tt = 0; tt < T_; tt++)
            ctxo += al[tt] * hcat[((size_t)b * T_ + tt) * 64 + t];
        float sv = ctxo, sq = ctxo * ctxo;
#pragma unroll
        for (int s_ = 1; s_ < 64; s_ <<= 1) {
            sv += __shfl_xor(sv, s_);
            sq += __shfl_xor(sq, s_);
        }
        float mu = sv * (1.f / 64.f);
        float var = sq * (1.f / 64.f) - mu * mu;
        float nv = (ctxo - mu) / sqrtf(var + 1e-5f) * lng[t] + lnb[t];
        ctx[t] = nv;
    }
    __syncthreads();
    if (t < 32) {
        float s = b1[t];
        for (int k = 0; k < 64; k++) s += ctx[k] * w1[k * 32 + t];
        a1[t] = fmaxf(s, 0.f);
    }
    __syncthreads();
    if (t < 3) {
        float s = b2[t];
        for (int k = 0; k < 32; k++) s += a1[k] * w2[k * 3 + t];
        out[b * 3 + t] = s;
    }
}

// ---------------------------------------------------------------------------
extern "C" void kernel_launch(void* const* d_in, const int* in_sizes, int n_in,
                              void* d_out, int out_size, void* d_ws, size_t ws_size,
                              hipStream_t stream) {
    const float* x          = (const float*)d_in[0];
    const float* spectral_w = (const float*)d_in[1];
    const float* gat_W      = (const float*)d_in[2];
    const float* gat_a      = (const float*)d_in[3];
    const float* pool_w     = (const float*)d_in[4];
    const float* pool_b     = (const float*)d_in[5];
    const float* lstm_Wi_f  = (const float*)d_in[6];
    const float* lstm_Wh_f  = (const float*)d_in[7];
    const float* lstm_b_f   = (const float*)d_in[8];
    const float* lstm_Wi_r  = (const float*)d_in[9];
    const float* lstm_Wh_r  = (const float*)d_in[10];
    const float* lstm_b_r   = (const float*)d_in[11];
    const float* ta_W       = (const float*)d_in[12];
    const float* ta_b       = (const float*)d_in[13];
    const float* ta_v       = (const float*)d_in[14];
    const float* ln_g       = (const float*)d_in[15];
    const float* ln_b       = (const float*)d_in[16];
    const float* fc1_w      = (const float*)d_in[17];
    const float* fc1_b      = (const float*)d_in[18];
    const float* fc2_w      = (const float*)d_in[19];
    const float* fc2_b      = (const float*)d_in[20];
    float* out = (float*)d_out;

    float* ws = (float*)d_ws;
    float* sw    = ws + 0;                         // 8192
    float* A     = ws + 8192;                      // 65536
    unsigned long long* amask = (unsigned long long*)(ws + 73728);  // 1024 u64
    float* Wh    = ws + 75776;                     // 8388608
    float* s1    = ws + 8464384;                   // 262144
    float* s2    = ws + 8726528;                   // 262144
    float* hpool = ws + 8988672;                   // 131072
    float* gx    = ws + 9119744;                   // 1048576
    float* hcat  = ws + 10168320;                  // 262144

    hipMemsetAsync(A, 0, (size_t)C_ * C_ * B_ * sizeof(float), stream);
    k_sw<<<C_, 64, 0, stream>>>(spectral_w, sw);
    k_phase1<<<dim3(B_, T_ / TC), 256, 0, stream>>>(x, sw, gat_W, gat_a, A, Wh, s1, s2);
    k_topk<<<B_, 64, 0, stream>>>(A, amask);
    k_gat<<<B_ * T_, 64, 0, stream>>>(Wh, s1, s2, amask, pool_w, pool_b, hpool);
    k_lstm_pre<<<2 * B_ * T_, 128, 0, stream>>>(hpool, lstm_Wi_f, lstm_b_f,
                                                lstm_Wi_r, lstm_b_r, gx);
    k_lstm_seq<<<2 * B_, 128, 0, stream>>>(gx, lstm_Wh_f, lstm_Wh_r, hcat);
    k_final<<<B_, 256, 0, stream>>>(hcat, ta_W, ta_b, ta_v, ln_g, ln_b,
                                    fc1_w, fc1_b, fc2_w, fc2_b, out);
}

// Round 2
// 517.760 us; speedup vs baseline: 1.1321x; 1.1321x over previous
//
#include <hip/hip_runtime.h>
#include <hip/hip_bf16.h>

// Dims
#define B_  16
#define T_  256
#define C_  64
#define F_  128
#define O_  32   // GO
#define H_  32
#define G4_ 128  // 4*H

typedef __attribute__((ext_vector_type(8))) short bfrag;
typedef __attribute__((ext_vector_type(4))) float f4acc;

__device__ __forceinline__ unsigned short f2bf(float v) {
    union { float f; unsigned u; } c; c.f = v;
    unsigned r = c.u + 0x7FFF + ((c.u >> 16) & 1);
    return (unsigned short)(r >> 16);
}
__device__ __forceinline__ float bf2f(unsigned short b) {
    union { float f; unsigned u; } c; c.u = ((unsigned)b) << 16; return c.f;
}
__device__ __forceinline__ float sigm_f(float x) {
    return __builtin_amdgcn_rcpf(1.f + __expf(-x));
}
__device__ __forceinline__ float tanh_f(float x) {
    float e = __expf(2.f * x);
    return 1.f - 2.f * __builtin_amdgcn_rcpf(e + 1.f);
}

// ---------------------------------------------------------------------------
// K0: softmax of spectral_w rows (64 rows of 128)
// ---------------------------------------------------------------------------
__global__ __launch_bounds__(64) void k_sw(const float* __restrict__ w,
                                           float* __restrict__ sw) {
    int c = blockIdx.x, lane = threadIdx.x;
    const float* row = w + c * F_;
    float v0 = row[lane], v1 = row[lane + 64];
    float m = fmaxf(v0, v1);
#pragma unroll
    for (int s = 1; s < 64; s <<= 1) m = fmaxf(m, __shfl_xor(m, s));
    float e0 = __expf(v0 - m), e1 = __expf(v1 - m);
    float s = e0 + e1;
#pragma unroll
    for (int s_ = 1; s_ < 64; s_ <<= 1) s += __shfl_xor(s, s_);
    sw[c * F_ + lane] = e0 / s;
    sw[c * F_ + lane + 64] = e1 / s;
}

// ---------------------------------------------------------------------------
// K1: MFMA phase1. split-bf16 (hi/lo) Hn planes in LDS.
//   A[b] += Hn Hn^T   (per-wave 2x2 quadrant of 16x16 tiles, frag reuse A==B)
//   Wh = diag(nrm) * (Hn @ W)  (W frags in regs), s1/s2 epilogue.
// grid (B, T/TCP), block 256.
// ---------------------------------------------------------------------------
#define TCP 4
#define PSTR 136   // bf16 elements per row (272 B): 16B-aligned, bank-uniform

#define MFMA16(a, b, c) __builtin_amdgcn_mfma_f32_16x16x32_bf16(a, b, c, 0, 0, 0)

__global__ __launch_bounds__(256) void k_phase1(
    const float* __restrict__ x, const float* __restrict__ sw,
    const float* __restrict__ gat_W, const float* __restrict__ gat_a,
    float* __restrict__ A, float* __restrict__ Wh,
    float* __restrict__ s1, float* __restrict__ s2) {
    const int b = blockIdx.x, tc = blockIdx.y, tid = threadIdx.x;
    const int wv = tid >> 6, lane = tid & 63;
    const int quad = lane >> 4, l16 = lane & 15;

    __shared__ unsigned short hhi[64 * PSTR];
    __shared__ unsigned short hlo[64 * PSTR];
    __shared__ float nrm[64];
    __shared__ float s1p[2][64], s2p[2][64];

    // sw regs (same (c,f) slice every t)
    float4 swr[8];
    {
        const float4* sw4 = (const float4*)sw;
#pragma unroll
        for (int i = 0; i < 8; i++) swr[i] = sw4[tid + 256 * i];
    }

    const int rt0 = (wv >> 1) * 2;  // row-tile base {0,2}
    const int ct0 = (wv & 1) * 2;   // col-tile base {0,2}
    const int jW = wv & 1;          // Wh col-tile

    // W fragments (hi/lo) for this wave's jW, ksteps 0..3, held in regs
    bfrag wfh[4], wfl[4];
    {
        const int n = l16 + 16 * jW;
#pragma unroll
        for (int k = 0; k < 4; k++) {
            union { unsigned short u[8]; bfrag v; } Hu, Lu;
#pragma unroll
            for (int u = 0; u < 8; u++) {
                float v = gat_W[(32 * k + quad * 8 + u) * O_ + n];
                unsigned short hb = f2bf(v);
                Hu.u[u] = hb;
                Lu.u[u] = f2bf(v - bf2f(hb));
            }
            wfh[k] = Hu.v;
            wfl[k] = Lu.v;
        }
    }
    const float ga1 = gat_a[l16 + 16 * jW];
    const float ga2 = gat_a[O_ + l16 + 16 * jW];

    f4acc accA[2][2];
#pragma unroll
    for (int i = 0; i < 2; i++)
#pragma unroll
        for (int j = 0; j < 2; j++) accA[i][j] = (f4acc){0.f, 0.f, 0.f, 0.f};

    for (int tt = 0; tt < TCP; ++tt) {
        const int t = tc * TCP + tt;
        const float4* xg = (const float4*)(x + ((size_t)(b * T_ + t) << 13));
        float4 xr[8];
#pragma unroll
        for (int i = 0; i < 8; i++) xr[i] = xg[tid + 256 * i];

        __syncthreads();  // (a) prev-t frag reads done before plane overwrite

        float invn_[8];
#pragma unroll
        for (int i = 0; i < 8; i++) {
            float4 v = xr[i], s = swr[i];
            v.x *= s.x; v.y *= s.y; v.z *= s.z; v.w *= s.w;
            xr[i] = v;
            float ss = v.x * v.x + v.y * v.y + v.z * v.z + v.w * v.w;
#pragma unroll
            for (int d = 1; d < 32; d <<= 1) ss += __shfl_xor(ss, d);
            float nv = sqrtf(ss) + 1e-8f;
            invn_[i] = 1.0f / nv;
            if ((tid & 31) == 0) nrm[(tid >> 5) + 8 * i] = nv;
        }
        // split + write planes: row c=(tid>>5)+8i, f = 4*(tid&31)
#pragma unroll
        for (int i = 0; i < 8; i++) {
            int c = (tid >> 5) + 8 * i;
            float4 v = xr[i];
            float iv = invn_[i];
            float a0 = v.x * iv, a1 = v.y * iv, a2 = v.z * iv, a3 = v.w * iv;
            union { unsigned short u[4]; unsigned long long q; } Hq, Lq;
            unsigned short h0 = f2bf(a0), h1 = f2bf(a1), h2 = f2bf(a2), h3 = f2bf(a3);
            Hq.u[0] = h0; Hq.u[1] = h1; Hq.u[2] = h2; Hq.u[3] = h3;
            Lq.u[0] = f2bf(a0 - bf2f(h0));
            Lq.u[1] = f2bf(a1 - bf2f(h1));
            Lq.u[2] = f2bf(a2 - bf2f(h2));
            Lq.u[3] = f2bf(a3 - bf2f(h3));
            int off = c * PSTR + 4 * (tid & 31);
            *(unsigned long long*)&hhi[off] = Hq.q;
            *(unsigned long long*)&hlo[off] = Lq.q;
        }
        __syncthreads();  // (b) planes ready

        f4acc accW0 = (f4acc){0.f, 0.f, 0.f, 0.f};
        f4acc accW1 = (f4acc){0.f, 0.f, 0.f, 0.f};
#pragma unroll
        for (int k = 0; k < 4; k++) {
            const int ko = 32 * k + 8 * quad;
            bfrag r0h = *(const bfrag*)&hhi[(rt0 * 16 + l16) * PSTR + ko];
            bfrag r0l = *(const bfrag*)&hlo[(rt0 * 16 + l16) * PSTR + ko];
            bfrag r1h = *(const bfrag*)&hhi[((rt0 + 1) * 16 + l16) * PSTR + ko];
            bfrag r1l = *(const bfrag*)&hlo[((rt0 + 1) * 16 + l16) * PSTR + ko];
            bfrag c0h = *(const bfrag*)&hhi[(ct0 * 16 + l16) * PSTR + ko];
            bfrag c0l = *(const bfrag*)&hlo[(ct0 * 16 + l16) * PSTR + ko];
            bfrag c1h = *(const bfrag*)&hhi[((ct0 + 1) * 16 + l16) * PSTR + ko];
            bfrag c1l = *(const bfrag*)&hlo[((ct0 + 1) * 16 + l16) * PSTR + ko];
            // A quadrant: 4 tiles x 3 products
            accA[0][0] = MFMA16(r0h, c0h, accA[0][0]);
            accA[0][0] = MFMA16(r0h, c0l, accA[0][0]);
            accA[0][0] = MFMA16(r0l, c0h, accA[0][0]);
            accA[0][1] = MFMA16(r0h, c1h, accA[0][1]);
            accA[0][1] = MFMA16(r0h, c1l, accA[0][1]);
            accA[0][1] = MFMA16(r0l, c1h, accA[0][1]);
            accA[1][0] = MFMA16(r1h, c0h, accA[1][0]);
            accA[1][0] = MFMA16(r1h, c0l, accA[1][0]);
            accA[1][0] = MFMA16(r1l, c0h, accA[1][0]);
            accA[1][1] = MFMA16(r1h, c1h, accA[1][1]);
            accA[1][1] = MFMA16(r1h, c1l, accA[1][1]);
            accA[1][1] = MFMA16(r1l, c1h, accA[1][1]);
            // Wh tiles (rows rt0, rt0+1; col jW), W frags in regs
            accW0 = MFMA16(r0h, wfh[k], accW0);
            accW0 = MFMA16(r0h, wfl[k], accW0);
            accW0 = MFMA16(r0l, wfh[k], accW0);
            accW1 = MFMA16(r1h, wfh[k], accW1);
            accW1 = MFMA16(r1h, wfl[k], accW1);
            accW1 = MFMA16(r1l, wfh[k], accW1);
        }
        // epilogue: scale rows by nrm, write Wh, reduce s1/s2 per row
        float* whout = Wh + (size_t)(b * T_ + t) * (C_ * O_);
#pragma unroll
        for (int i2 = 0; i2 < 2; i2++) {
            f4acc aw = i2 ? accW1 : accW0;
#pragma unroll
            for (int r = 0; r < 4; r++) {
                int row = (rt0 + i2) * 16 + quad * 4 + r;
                float val = aw[r] * nrm[row];
                whout[row * O_ + l16 + 16 * jW] = val;
                float v1 = val * ga1, v2 = val * ga2;
#pragma unroll
                for (int d = 1; d < 16; d <<= 1) {
                    v1 += __shfl_xor(v1, d);
                    v2 += __shfl_xor(v2, d);
                }
                if (l16 == 0) { s1p[jW][row] = v1; s2p[jW][row] = v2; }
            }
        }
        __syncthreads();  // (c) s1p/s2p ready
        if (tid < 64) {
            s1[(b * T_ + t) * C_ + tid] = s1p[0][tid] + s1p[1][tid];
            s2[(b * T_ + t) * C_ + tid] = s2p[0][tid] + s2p[1][tid];
        }
    }
    // block-end: quadrants disjoint -> direct atomicAdd
#pragma unroll
    for (int i2 = 0; i2 < 2; i2++)
#pragma unroll
        for (int j2 = 0; j2 < 2; j2++)
#pragma unroll
            for (int r = 0; r < 4; r++) {
                int row = (rt0 + i2) * 16 + quad * 4 + r;
                int col = (ct0 + j2) * 16 + l16;
                atomicAdd(&A[b * (C_ * C_) + row * C_ + col], accA[i2][j2][r]);
            }
}

// ---------------------------------------------------------------------------
// K2: top-4 selection + symmetrize -> amask bitmask per (b,c). grid B, block 64
// ---------------------------------------------------------------------------
__global__ __launch_bounds__(64) void k_topk(const float* __restrict__ A,
                                             unsigned long long* __restrict__ amask) {
    int b = blockIdx.x;
    int c = threadIdx.x;
    __shared__ unsigned long long tk[C_];
    const float* row = A + b * (C_ * C_) + c * C_;
    unsigned long long sel = 0ULL;
    for (int r = 0; r < 4; r++) {
        float best = -1e30f;
        int bi = 0;
        for (int d = 0; d < C_; d++) {
            if (sel & (1ULL << d)) continue;
            float v = row[d];
            if (v > best) { best = v; bi = d; }
        }
        sel |= (1ULL << bi);
    }
    unsigned long long t = sel & ~(1ULL << c);
    tk[c] = t;
    __syncthreads();
    unsigned long long sym = t;
    for (int d = 0; d < C_; d++)
        if ((tk[d] >> c) & 1ULL) sym |= (1ULL << d);
    unsigned long long m = (1ULL << c);
    unsigned long long s2 = sym;
    while (s2) {
        int d = __ffsll(s2) - 1;
        s2 &= s2 - 1;
        if (row[d] > 0.f) m |= (1ULL << d);
    }
    amask[b * C_ + c] = m;
}

// ---------------------------------------------------------------------------
// K3: GAT attention + relu + pooling. block 256 = 4 waves = 4 t's. grid B*T/4.
// Neighbor Wh rows gathered from global (L2); pooled via LDS transpose.
// ---------------------------------------------------------------------------
__global__ __launch_bounds__(256) void k_gat(
    const float* __restrict__ Wh, const float* __restrict__ s1,
    const float* __restrict__ s2, const unsigned long long* __restrict__ amask,
    const float* __restrict__ pool_w, const float* __restrict__ pool_b,
    float* __restrict__ hout) {
    int tg = blockIdx.x;
    int wv = threadIdx.x >> 6, c = threadIdx.x & 63;
    int bt = tg * 4 + wv;
    int b = bt >> 8;
    __shared__ float buf[4][C_][33];
    __shared__ float s2s[4][C_];

    s2s[wv][c] = s2[bt * C_ + c];
    float s1c = s1[bt * C_ + c];
    unsigned long long m = amask[b * C_ + c];
    __syncthreads();

    float mx = -1e30f;
    unsigned long long mm = m;
    while (mm) {
        int d = __ffsll(mm) - 1; mm &= mm - 1;
        float v = s1c + s2s[wv][d];
        v = v > 0.f ? v : 0.2f * v;
        mx = fmaxf(mx, v);
    }
    float ssum = 0.f;
    mm = m;
    while (mm) {
        int d = __ffsll(mm) - 1; mm &= mm - 1;
        float v = s1c + s2s[wv][d];
        v = v > 0.f ? v : 0.2f * v;
        ssum += __expf(v - mx);
    }
    float inv = 1.0f / ssum;
    float g[O_];
#pragma unroll
    for (int i = 0; i < O_; i++) g[i] = 0.f;
    mm = m;
    while (mm) {
        int d = __ffsll(mm) - 1; mm &= mm - 1;
        float v = s1c + s2s[wv][d];
        v = v > 0.f ? v : 0.2f * v;
        float a = __expf(v - mx);
        const float4* wr = (const float4*)(Wh + (size_t)bt * (C_ * O_) + d * O_);
#pragma unroll
        for (int q = 0; q < 8; q++) {
            float4 w4 = wr[q];
            g[4 * q + 0] += a * w4.x;
            g[4 * q + 1] += a * w4.y;
            g[4 * q + 2] += a * w4.z;
            g[4 * q + 3] += a * w4.w;
        }
    }
    float lg = pool_b[0];
#pragma unroll
    for (int i = 0; i < O_; i++) {
        g[i] = fmaxf(g[i] * inv, 0.f);
        lg += g[i] * pool_w[i];
    }
    float wmx = lg;
#pragma unroll
    for (int s = 1; s < 64; s <<= 1) wmx = fmaxf(wmx, __shfl_xor(wmx, s));
    float we = __expf(lg - wmx);
    float wsum = we;
#pragma unroll
    for (int s = 1; s < 64; s <<= 1) wsum += __shfl_xor(wsum, s);
    float wcf = we / wsum;
#pragma unroll
    for (int i = 0; i < O_; i++) buf[wv][c][i] = g[i] * wcf;
    __syncthreads();
    {
        int wt = threadIdx.x >> 6, o = threadIdx.x & 31, hf = (threadIdx.x >> 5) & 1;
        float sacc = 0.f;
#pragma unroll 8
        for (int d = hf * 32; d < hf * 32 + 32; d++) sacc += buf[wt][d][o];
        sacc += __shfl_xor(sacc, 32);
        if (hf == 0) hout[(tg * 4 + wt) * O_ + o] = sacc;
    }
}

// ---------------------------------------------------------------------------
// K4a: LSTM input projection gx = h @ Wi + b. grid 2*B*T, block 128
// ---------------------------------------------------------------------------
__global__ __launch_bounds__(128) void k_lstm_pre(
    const float* __restrict__ hin,
    const float* __restrict__ Wi_f, const float* __restrict__ b_f,
    const float* __restrict__ Wi_r, const float* __restrict__ b_r,
    float* __restrict__ gx) {
    int id = blockIdx.x;
    int dir = id >> 12;
    int bt = id & 4095;
    const float* Wi = dir ? Wi_r : Wi_f;
    const float* bb = dir ? b_r : b_f;
    int g = threadIdx.x;
    __shared__ float hs[H_];
    if (g < H_) hs[g] = hin[bt * O_ + g];
    __syncthreads();
    float acc = bb[g];
#pragma unroll
    for (int k = 0; k < H_; k++) acc += hs[k] * Wi[k * G4_ + g];
    gx[((size_t)dir * 4096 + bt) * G4_ + g] = acc;
}

// ---------------------------------------------------------------------------
// K4b: LSTM recurrence — single wave per (dir,b), no __syncthreads.
// lane l holds gates l and l+64; Wh columns in regs; h broadcast via shfl.
// grid 2*B, block 64.
// ---------------------------------------------------------------------------
__global__ __launch_bounds__(64) void k_lstm_seq(
    const float* __restrict__ gx,
    const float* __restrict__ Whf, const float* __restrict__ Whr,
    float* __restrict__ hcat) {
    int dir = blockIdx.x & 1, b = blockIdx.x >> 1;
    int lane = threadIdx.x;
    const float* W = dir ? Whr : Whf;
    float wA[H_], wB[H_];
#pragma unroll
    for (int k = 0; k < H_; k++) {
        wA[k] = W[k * G4_ + lane];
        wB[k] = W[k * G4_ + lane + 64];
    }
    const float* gxb = gx + ((size_t)dir * 4096 + b * T_) * G4_;
    float h = 0.f, cst = 0.f;
    const int dt = dir ? -1 : 1;
    int t = dir ? (T_ - 1) : 0;
    float g0n = gxb[t * G4_ + lane], g1n = gxb[t * G4_ + lane + 64];
    for (int s = 0; s < T_; s++) {
        float g0 = g0n, g1 = g1n;
        int tn = t + dt;
        if (s < T_ - 1) {
            g0n = gxb[tn * G4_ + lane];
            g1n = gxb[tn * G4_ + lane + 64];
        }
#pragma unroll
        for (int k = 0; k < H_; k++) {
            float hk = __shfl(h, k);
            g0 += hk * wA[k];
            g1 += hk * wB[k];
        }
        // lane<32: g0=i, g1=g ; lane>=32: g0=f, g1=o
        float fx = __shfl(g0, (lane & 31) + 32);
        float ox = __shfl(g1, (lane & 31) + 32);
        float si = sigm_f(g0);
        float sf = sigm_f(fx);
        float so = sigm_f(ox);
        cst = sf * cst + si * tanh_f(g1);
        float hn = so * tanh_f(cst);
        h = hn;
        if (lane < H_) hcat[((size_t)(b * T_) + t) * (2 * H_) + dir * H_ + lane] = hn;
        t = tn;
    }
}

// ---------------------------------------------------------------------------
// K5: temporal attention + LN + fc1 + fc2 -> out (B,3). grid B, block 256.
// ---------------------------------------------------------------------------
__global__ __launch_bounds__(256) void k_final(
    const float* __restrict__ hcat,
    const float* __restrict__ taW, const float* __restrict__ tab,
    const float* __restrict__ tav,
    const float* __restrict__ lng, const float* __restrict__ lnb,
    const float* __restrict__ w1, const float* __restrict__ b1,
    const float* __restrict__ w2, const float* __restrict__ b2,
    float* __restrict__ out) {
    int b = blockIdx.x;
    int t = threadIdx.x;
    __shared__ float Wl[64 * 64];
    __shared__ float al[T_];
    __shared__ float wred[4];
    __shared__ float ctxp[4][64];
    __shared__ float ctx[64];
    __shared__ float a1[32];
    for (int i = t; i < 4096; i += 256) Wl[i] = taW[i];
    float4 hr[16];
    const float4* hb = (const float4*)(hcat + ((size_t)b * T_ + t) * 64);
#pragma unroll
    for (int i = 0; i < 16; i++) hr[i] = hb[i];
    __syncthreads();
    float sc = 0.f;
    for (int j = 0; j < 64; j++) {
        float s = tab[j];
#pragma unroll
        for (int k4 = 0; k4 < 16; k4++) {
            float4 h4 = hr[k4];
            const float* wcol = &Wl[(4 * k4) * 64 + j];
            s += h4.x * wcol[0] + h4.y * wcol[64] + h4.z * wcol[128] + h4.w * wcol[192];
        }
        sc += tanhf(s) * tav[j];
    }
    sc *= (1.0f / 1.5f);
    int wave = t >> 6, lane = t & 63;
    float m = sc;
#pragma unroll
    for (int s_ = 1; s_ < 64; s_ <<= 1) m = fmaxf(m, __shfl_xor(m, s_));
    if (lane == 0) wred[wave] = m;
    __syncthreads();
    m = fmaxf(fmaxf(wred[0], wred[1]), fmaxf(wred[2], wred[3]));
    float e = __expf(sc - m);
    float ssum = e;
#pragma unroll
    for (int s_ = 1; s_ < 64; s_ <<= 1) ssum += __shfl_xor(ssum, s_);
    __syncthreads();
    if (lane == 0) wred[wave] = ssum;
    __syncthreads();
    float S = wred[0] + wred[1] + wred[2] + wred[3];
    al[t] = e / S;
    __syncthreads();
    // ctx partials: thread = (part = t>>6, o = t&63)
    {
        int o = t & 63, part = t >> 6;
        float cacc = 0.f;
        for (int tt = part * 64; tt < part * 64 + 64; tt++)
            cacc += al[tt] * hcat[((size_t)b * T_ + tt) * 64 + o];
        ctxp[part][o] = cacc;
    }
    __syncthreads();
    if (t < 64) {
        float ctxo = ctxp[0][t] + ctxp[1][t] + ctxp[2][t] + ctxp[3][t];
        float sv = ctxo, sq = ctxo * ctxo;
#pragma unroll
        for (int s_ = 1; s_ < 64; s_ <<= 1) {
            sv += __shfl_xor(sv, s_);
            sq += __shfl_xor(sq, s_);
        }
        float mu = sv * (1.f / 64.f);
        float var = sq * (1.f / 64.f) - mu * mu;
        ctx[t] = (ctxo - mu) / sqrtf(var + 1e-5f) * lng[t] + lnb[t];
    }
    __syncthreads();
    if (t < 32) {
        float s = b1[t];
        for (int k = 0; k < 64; k++) s += ctx[k] * w1[k * 32 + t];
        a1[t] = fmaxf(s, 0.f);
    }
    __syncthreads();
    if (t < 3) {
        float s = b2[t];
        for (int k = 0; k < 32; k++) s += a1[k] * w2[k * 3 + t];
        out[b * 3 + t] = s;
    }
}

// ---------------------------------------------------------------------------
extern "C" void kernel_launch(void* const* d_in, const int* in_sizes, int n_in,
                              void* d_out, int out_size, void* d_ws, size_t ws_size,
                              hipStream_t stream) {
    const float* x          = (const float*)d_in[0];
    const float* spectral_w = (const float*)d_in[1];
    const float* gat_W      = (const float*)d_in[2];
    const float* gat_a      = (const float*)d_in[3];
    const float* pool_w     = (const float*)d_in[4];
    const float* pool_b     = (const float*)d_in[5];
    const float* lstm_Wi_f  = (const float*)d_in[6];
    const float* lstm_Wh_f  = (const float*)d_in[7];
    const float* lstm_b_f   = (const float*)d_in[8];
    const float* lstm_Wi_r  = (const float*)d_in[9];
    const float* lstm_Wh_r  = (const float*)d_in[10];
    const float* lstm_b_r   = (const float*)d_in[11];
    const float* ta_W       = (const float*)d_in[12];
    const float* ta_b       = (const float*)d_in[13];
    const float* ta_v       = (const float*)d_in[14];
    const float* ln_g       = (const float*)d_in[15];
    const float* ln_b       = (const float*)d_in[16];
    const float* fc1_w      = (const float*)d_in[17];
    const float* fc1_b      = (const float*)d_in[18];
    const float* fc2_w      = (const float*)d_in[19];
    const float* fc2_b      = (const float*)d_in[20];
    float* out = (float*)d_out;

    float* ws = (float*)d_ws;
    float* sw    = ws + 0;                         // 8192
    float* A     = ws + 8192;                      // 65536
    unsigned long long* amask = (unsigned long long*)(ws + 73728);  // 1024 u64
    float* Wh    = ws + 75776;                     // 8388608
    float* s1    = ws + 8464384;                   // 262144
    float* s2    = ws + 8726528;                   // 262144
    float* hpool = ws + 8988672;                   // 131072
    float* gx    = ws + 9119744;                   // 1048576
    float* hcat  = ws + 10168320;                  // 262144

    hipMemsetAsync(A, 0, (size_t)C_ * C_ * B_ * sizeof(float), stream);
    k_sw<<<C_, 64, 0, stream>>>(spectral_w, sw);
    k_phase1<<<dim3(B_, T_ / TCP), 256, 0, stream>>>(x, sw, gat_W, gat_a, A, Wh, s1, s2);
    k_topk<<<B_, 64, 0, stream>>>(A, amask);
    k_gat<<<B_ * T_ / 4, 256, 0, stream>>>(Wh, s1, s2, amask, pool_w, pool_b, hpool);
    k_lstm_pre<<<2 * B_ * T_, 128, 0, stream>>>(hpool, lstm_Wi_f, lstm_b_f,
                                                lstm_Wi_r, lstm_b_r, gx);
    k_lstm_seq<<<2 * B_, 64, 0, stream>>>(gx, lstm_Wh_f, lstm_Wh_r, hcat);
    k_final<<<B_, 256, 0, stream>>>(hcat, ta_W, ta_b, ta_v, ln_g, ln_b,
                                    fc1_w, fc1_b, fc2_w, fc2_b, out);
}

// Round 3
// 454.032 us; speedup vs baseline: 1.2910x; 1.1404x over previous
//
#include <hip/hip_runtime.h>
#include <hip/hip_bf16.h>

// Dims
#define B_  16
#define T_  256
#define C_  64
#define F_  128
#define O_  32   // GO
#define H_  32
#define G4_ 128  // 4*H

typedef __attribute__((ext_vector_type(8))) short bfrag;
typedef __attribute__((ext_vector_type(4))) float f4acc;

__device__ __forceinline__ unsigned short f2bf(float v) {
    union { float f; unsigned u; } c; c.f = v;
    unsigned r = c.u + 0x7FFF + ((c.u >> 16) & 1);
    return (unsigned short)(r >> 16);
}
__device__ __forceinline__ float bf2f(unsigned short b) {
    union { float f; unsigned u; } c; c.u = ((unsigned)b) << 16; return c.f;
}
__device__ __forceinline__ float sigm_f(float x) {
    return __builtin_amdgcn_rcpf(1.f + __expf(-x));
}
__device__ __forceinline__ float tanh_f(float x) {
    float e = __expf(2.f * x);
    return 1.f - 2.f * __builtin_amdgcn_rcpf(e + 1.f);
}
__device__ __forceinline__ float readlane_f(float v, int l) {
    return __int_as_float(__builtin_amdgcn_readlane(__float_as_int(v), l));
}

// ---------------------------------------------------------------------------
// K0: softmax of spectral_w rows (64 rows of 128)
// ---------------------------------------------------------------------------
__global__ __launch_bounds__(64) void k_sw(const float* __restrict__ w,
                                           float* __restrict__ sw) {
    int c = blockIdx.x, lane = threadIdx.x;
    const float* row = w + c * F_;
    float v0 = row[lane], v1 = row[lane + 64];
    float m = fmaxf(v0, v1);
#pragma unroll
    for (int s = 1; s < 64; s <<= 1) m = fmaxf(m, __shfl_xor(m, s));
    float e0 = __expf(v0 - m), e1 = __expf(v1 - m);
    float s = e0 + e1;
#pragma unroll
    for (int s_ = 1; s_ < 64; s_ <<= 1) s += __shfl_xor(s, s_);
    sw[c * F_ + lane] = e0 / s;
    sw[c * F_ + lane + 64] = e1 / s;
}

// ---------------------------------------------------------------------------
// K1: MFMA phase1. split-bf16 (hi/lo) Hn planes in LDS.
//   A[b] += Hn Hn^T   (per-wave 2x2 quadrant of 16x16 tiles, frag reuse A==B)
//   Wh = diag(nrm) * (Hn @ W)  (W frags in regs), s1/s2 epilogue.
// grid (B, T/TCP), block 256.
// ---------------------------------------------------------------------------
#define TCP 4
#define PSTR 136   // bf16 elements per row (272 B): 16B-aligned, bank-uniform

#define MFMA16(a, b, c) __builtin_amdgcn_mfma_f32_16x16x32_bf16(a, b, c, 0, 0, 0)

__global__ __launch_bounds__(256) void k_phase1(
    const float* __restrict__ x, const float* __restrict__ sw,
    const float* __restrict__ gat_W, const float* __restrict__ gat_a,
    float* __restrict__ A, float* __restrict__ Wh,
    float* __restrict__ s1, float* __restrict__ s2) {
    const int b = blockIdx.x, tc = blockIdx.y, tid = threadIdx.x;
    const int wv = tid >> 6, lane = tid & 63;
    const int quad = lane >> 4, l16 = lane & 15;

    __shared__ unsigned short hhi[64 * PSTR];
    __shared__ unsigned short hlo[64 * PSTR];
    __shared__ float nrm[64];
    __shared__ float s1p[2][64], s2p[2][64];

    // sw regs (same (c,f) slice every t)
    float4 swr[8];
    {
        const float4* sw4 = (const float4*)sw;
#pragma unroll
        for (int i = 0; i < 8; i++) swr[i] = sw4[tid + 256 * i];
    }

    const int rt0 = (wv >> 1) * 2;  // row-tile base {0,2}
    const int ct0 = (wv & 1) * 2;   // col-tile base {0,2}
    const int jW = wv & 1;          // Wh col-tile

    // W fragments (hi/lo) for this wave's jW, ksteps 0..3, held in regs
    bfrag wfh[4], wfl[4];
    {
        const int n = l16 + 16 * jW;
#pragma unroll
        for (int k = 0; k < 4; k++) {
            union { unsigned short u[8]; bfrag v; } Hu, Lu;
#pragma unroll
            for (int u = 0; u < 8; u++) {
                float v = gat_W[(32 * k + quad * 8 + u) * O_ + n];
                unsigned short hb = f2bf(v);
                Hu.u[u] = hb;
                Lu.u[u] = f2bf(v - bf2f(hb));
            }
            wfh[k] = Hu.v;
            wfl[k] = Lu.v;
        }
    }
    const float ga1 = gat_a[l16 + 16 * jW];
    const float ga2 = gat_a[O_ + l16 + 16 * jW];

    f4acc accA[2][2];
#pragma unroll
    for (int i = 0; i < 2; i++)
#pragma unroll
        for (int j = 0; j < 2; j++) accA[i][j] = (f4acc){0.f, 0.f, 0.f, 0.f};

    for (int tt = 0; tt < TCP; ++tt) {
        const int t = tc * TCP + tt;
        const float4* xg = (const float4*)(x + ((size_t)(b * T_ + t) << 13));
        float4 xr[8];
#pragma unroll
        for (int i = 0; i < 8; i++) xr[i] = xg[tid + 256 * i];

        __syncthreads();  // (a) prev-t frag reads done before plane overwrite

        float invn_[8];
#pragma unroll
        for (int i = 0; i < 8; i++) {
            float4 v = xr[i], s = swr[i];
            v.x *= s.x; v.y *= s.y; v.z *= s.z; v.w *= s.w;
            xr[i] = v;
            float ss = v.x * v.x + v.y * v.y + v.z * v.z + v.w * v.w;
#pragma unroll
            for (int d = 1; d < 32; d <<= 1) ss += __shfl_xor(ss, d);
            float nv = sqrtf(ss) + 1e-8f;
            invn_[i] = 1.0f / nv;
            if ((tid & 31) == 0) nrm[(tid >> 5) + 8 * i] = nv;
        }
        // split + write planes: row c=(tid>>5)+8i, f = 4*(tid&31)
#pragma unroll
        for (int i = 0; i < 8; i++) {
            int c = (tid >> 5) + 8 * i;
            float4 v = xr[i];
            float iv = invn_[i];
            float a0 = v.x * iv, a1 = v.y * iv, a2 = v.z * iv, a3 = v.w * iv;
            union { unsigned short u[4]; unsigned long long q; } Hq, Lq;
            unsigned short h0 = f2bf(a0), h1 = f2bf(a1), h2 = f2bf(a2), h3 = f2bf(a3);
            Hq.u[0] = h0; Hq.u[1] = h1; Hq.u[2] = h2; Hq.u[3] = h3;
            Lq.u[0] = f2bf(a0 - bf2f(h0));
            Lq.u[1] = f2bf(a1 - bf2f(h1));
            Lq.u[2] = f2bf(a2 - bf2f(h2));
            Lq.u[3] = f2bf(a3 - bf2f(h3));
            int off = c * PSTR + 4 * (tid & 31);
            *(unsigned long long*)&hhi[off] = Hq.q;
            *(unsigned long long*)&hlo[off] = Lq.q;
        }
        __syncthreads();  // (b) planes ready

        f4acc accW0 = (f4acc){0.f, 0.f, 0.f, 0.f};
        f4acc accW1 = (f4acc){0.f, 0.f, 0.f, 0.f};
#pragma unroll
        for (int k = 0; k < 4; k++) {
            const int ko = 32 * k + 8 * quad;
            bfrag r0h = *(const bfrag*)&hhi[(rt0 * 16 + l16) * PSTR + ko];
            bfrag r0l = *(const bfrag*)&hlo[(rt0 * 16 + l16) * PSTR + ko];
            bfrag r1h = *(const bfrag*)&hhi[((rt0 + 1) * 16 + l16) * PSTR + ko];
            bfrag r1l = *(const bfrag*)&hlo[((rt0 + 1) * 16 + l16) * PSTR + ko];
            bfrag c0h = *(const bfrag*)&hhi[(ct0 * 16 + l16) * PSTR + ko];
            bfrag c0l = *(const bfrag*)&hlo[(ct0 * 16 + l16) * PSTR + ko];
            bfrag c1h = *(const bfrag*)&hhi[((ct0 + 1) * 16 + l16) * PSTR + ko];
            bfrag c1l = *(const bfrag*)&hlo[((ct0 + 1) * 16 + l16) * PSTR + ko];
            // A quadrant: 4 tiles x 3 products
            accA[0][0] = MFMA16(r0h, c0h, accA[0][0]);
            accA[0][0] = MFMA16(r0h, c0l, accA[0][0]);
            accA[0][0] = MFMA16(r0l, c0h, accA[0][0]);
            accA[0][1] = MFMA16(r0h, c1h, accA[0][1]);
            accA[0][1] = MFMA16(r0h, c1l, accA[0][1]);
            accA[0][1] = MFMA16(r0l, c1h, accA[0][1]);
            accA[1][0] = MFMA16(r1h, c0h, accA[1][0]);
            accA[1][0] = MFMA16(r1h, c0l, accA[1][0]);
            accA[1][0] = MFMA16(r1l, c0h, accA[1][0]);
            accA[1][1] = MFMA16(r1h, c1h, accA[1][1]);
            accA[1][1] = MFMA16(r1h, c1l, accA[1][1]);
            accA[1][1] = MFMA16(r1l, c1h, accA[1][1]);
            // Wh tiles (rows rt0, rt0+1; col jW), W frags in regs
            accW0 = MFMA16(r0h, wfh[k], accW0);
            accW0 = MFMA16(r0h, wfl[k], accW0);
            accW0 = MFMA16(r0l, wfh[k], accW0);
            accW1 = MFMA16(r1h, wfh[k], accW1);
            accW1 = MFMA16(r1h, wfl[k], accW1);
            accW1 = MFMA16(r1l, wfh[k], accW1);
        }
        // epilogue: scale rows by nrm, write Wh, reduce s1/s2 per row
        float* whout = Wh + (size_t)(b * T_ + t) * (C_ * O_);
#pragma unroll
        for (int i2 = 0; i2 < 2; i2++) {
            f4acc aw = i2 ? accW1 : accW0;
#pragma unroll
            for (int r = 0; r < 4; r++) {
                int row = (rt0 + i2) * 16 + quad * 4 + r;
                float val = aw[r] * nrm[row];
                whout[row * O_ + l16 + 16 * jW] = val;
                float v1 = val * ga1, v2 = val * ga2;
#pragma unroll
                for (int d = 1; d < 16; d <<= 1) {
                    v1 += __shfl_xor(v1, d);
                    v2 += __shfl_xor(v2, d);
                }
                if (l16 == 0) { s1p[jW][row] = v1; s2p[jW][row] = v2; }
            }
        }
        __syncthreads();  // (c) s1p/s2p ready
        if (tid < 64) {
            s1[(b * T_ + t) * C_ + tid] = s1p[0][tid] + s1p[1][tid];
            s2[(b * T_ + t) * C_ + tid] = s2p[0][tid] + s2p[1][tid];
        }
    }
    // block-end: quadrants disjoint -> direct atomicAdd
#pragma unroll
    for (int i2 = 0; i2 < 2; i2++)
#pragma unroll
        for (int j2 = 0; j2 < 2; j2++)
#pragma unroll
            for (int r = 0; r < 4; r++) {
                int row = (rt0 + i2) * 16 + quad * 4 + r;
                int col = (ct0 + j2) * 16 + l16;
                atomicAdd(&A[b * (C_ * C_) + row * C_ + col], accA[i2][j2][r]);
            }
}

// ---------------------------------------------------------------------------
// K2: top-4 selection + symmetrize -> amask bitmask per (b,c). grid B, block 64
// ---------------------------------------------------------------------------
__global__ __launch_bounds__(64) void k_topk(const float* __restrict__ A,
                                             unsigned long long* __restrict__ amask) {
    int b = blockIdx.x;
    int c = threadIdx.x;
    __shared__ unsigned long long tk[C_];
    const float* row = A + b * (C_ * C_) + c * C_;
    unsigned long long sel = 0ULL;
    for (int r = 0; r < 4; r++) {
        float best = -1e30f;
        int bi = 0;
        for (int d = 0; d < C_; d++) {
            if (sel & (1ULL << d)) continue;
            float v = row[d];
            if (v > best) { best = v; bi = d; }
        }
        sel |= (1ULL << bi);
    }
    unsigned long long t = sel & ~(1ULL << c);
    tk[c] = t;
    __syncthreads();
    unsigned long long sym = t;
    for (int d = 0; d < C_; d++)
        if ((tk[d] >> c) & 1ULL) sym |= (1ULL << d);
    unsigned long long m = (1ULL << c);
    unsigned long long s2 = sym;
    while (s2) {
        int d = __ffsll(s2) - 1;
        s2 &= s2 - 1;
        if (row[d] > 0.f) m |= (1ULL << d);
    }
    amask[b * C_ + c] = m;
}

// ---------------------------------------------------------------------------
// K3: GAT attention + relu + pooling. block 256 = 4 waves = 4 t's. grid B*T/4.
// ---------------------------------------------------------------------------
__global__ __launch_bounds__(256) void k_gat(
    const float* __restrict__ Wh, const float* __restrict__ s1,
    const float* __restrict__ s2, const unsigned long long* __restrict__ amask,
    const float* __restrict__ pool_w, const float* __restrict__ pool_b,
    float* __restrict__ hout) {
    int tg = blockIdx.x;
    int wv = threadIdx.x >> 6, c = threadIdx.x & 63;
    int bt = tg * 4 + wv;
    int b = bt >> 8;
    __shared__ float buf[4][C_][33];
    __shared__ float s2s[4][C_];

    s2s[wv][c] = s2[bt * C_ + c];
    float s1c = s1[bt * C_ + c];
    unsigned long long m = amask[b * C_ + c];
    __syncthreads();

    float mx = -1e30f;
    unsigned long long mm = m;
    while (mm) {
        int d = __ffsll(mm) - 1; mm &= mm - 1;
        float v = s1c + s2s[wv][d];
        v = v > 0.f ? v : 0.2f * v;
        mx = fmaxf(mx, v);
    }
    float ssum = 0.f;
    mm = m;
    while (mm) {
        int d = __ffsll(mm) - 1; mm &= mm - 1;
        float v = s1c + s2s[wv][d];
        v = v > 0.f ? v : 0.2f * v;
        ssum += __expf(v - mx);
    }
    float inv = 1.0f / ssum;
    float g[O_];
#pragma unroll
    for (int i = 0; i < O_; i++) g[i] = 0.f;
    mm = m;
    while (mm) {
        int d = __ffsll(mm) - 1; mm &= mm - 1;
        float v = s1c + s2s[wv][d];
        v = v > 0.f ? v : 0.2f * v;
        float a = __expf(v - mx);
        const float4* wr = (const float4*)(Wh + (size_t)bt * (C_ * O_) + d * O_);
#pragma unroll
        for (int q = 0; q < 8; q++) {
            float4 w4 = wr[q];
            g[4 * q + 0] += a * w4.x;
            g[4 * q + 1] += a * w4.y;
            g[4 * q + 2] += a * w4.z;
            g[4 * q + 3] += a * w4.w;
        }
    }
    float lg = pool_b[0];
#pragma unroll
    for (int i = 0; i < O_; i++) {
        g[i] = fmaxf(g[i] * inv, 0.f);
        lg += g[i] * pool_w[i];
    }
    float wmx = lg;
#pragma unroll
    for (int s = 1; s < 64; s <<= 1) wmx = fmaxf(wmx, __shfl_xor(wmx, s));
    float we = __expf(lg - wmx);
    float wsum = we;
#pragma unroll
    for (int s = 1; s < 64; s <<= 1) wsum += __shfl_xor(wsum, s);
    float wcf = we / wsum;
#pragma unroll
    for (int i = 0; i < O_; i++) buf[wv][c][i] = g[i] * wcf;
    __syncthreads();
    {
        int wt = threadIdx.x >> 6, o = threadIdx.x & 31, hf = (threadIdx.x >> 5) & 1;
        float sacc = 0.f;
#pragma unroll 8
        for (int d = hf * 32; d < hf * 32 + 32; d++) sacc += buf[wt][d][o];
        sacc += __shfl_xor(sacc, 32);
        if (hf == 0) hout[(tg * 4 + wt) * O_ + o] = sacc;
    }
}

// ---------------------------------------------------------------------------
// K4a: LSTM input projection gx = h @ Wi + b. grid 2*B*T, block 128
// ---------------------------------------------------------------------------
__global__ __launch_bounds__(128) void k_lstm_pre(
    const float* __restrict__ hin,
    const float* __restrict__ Wi_f, const float* __restrict__ b_f,
    const float* __restrict__ Wi_r, const float* __restrict__ b_r,
    float* __restrict__ gx) {
    int id = blockIdx.x;
    int dir = id >> 12;
    int bt = id & 4095;
    const float* Wi = dir ? Wi_r : Wi_f;
    const float* bb = dir ? b_r : b_f;
    int g = threadIdx.x;
    __shared__ float hs[H_];
    if (g < H_) hs[g] = hin[bt * O_ + g];
    __syncthreads();
    float acc = bb[g];
#pragma unroll
    for (int k = 0; k < H_; k++) acc += hs[k] * Wi[k * G4_ + g];
    gx[((size_t)dir * 4096 + bt) * G4_ + g] = acc;
}

// ---------------------------------------------------------------------------
// K4b: LSTM recurrence — single wave per (dir,b), no LDS in the dot product.
// lane l<32: gates i_l (g0), g_l (g1); lane>=32: f_{l-32}, o_{l-32}.
// h broadcast via v_readlane (compile-time lane idx -> SGPR operand FMA).
// __launch_bounds__(64,1): full VGPR budget so wA/wB stay in registers.
// grid 2*B, block 64.
// ---------------------------------------------------------------------------
__global__ __launch_bounds__(64, 1) void k_lstm_seq(
    const float* __restrict__ gx,
    const float* __restrict__ Whf, const float* __restrict__ Whr,
    float* __restrict__ hcat) {
    int dir = blockIdx.x & 1, b = blockIdx.x >> 1;
    int lane = threadIdx.x;
    const float* W = dir ? Whr : Whf;
    float wA[H_], wB[H_];
#pragma unroll
    for (int k = 0; k < H_; k++) {
        wA[k] = W[k * G4_ + lane];
        wB[k] = W[k * G4_ + lane + 64];
    }
    const float* gxb = gx + ((size_t)dir * 4096 + b * T_) * G4_;
    float h = 0.f, cst = 0.f;
    const int dt = dir ? -1 : 1;
    int t = dir ? (T_ - 1) : 0;
    float g0n = gxb[t * G4_ + lane], g1n = gxb[t * G4_ + lane + 64];
    for (int s = 0; s < T_; s++) {
        int tn = t + dt;
        // 4-way split accumulators: dependent-FMA chain length 8, not 32
        float a0 = g0n, a1 = 0.f, a2 = 0.f, a3 = 0.f;
        float c0 = g1n, c1 = 0.f, c2 = 0.f, c3 = 0.f;
        if (s < T_ - 1) {
            g0n = gxb[tn * G4_ + lane];
            g1n = gxb[tn * G4_ + lane + 64];
        }
#pragma unroll
        for (int k = 0; k < H_; k += 4) {
            float h0 = readlane_f(h, k);
            float h1 = readlane_f(h, k + 1);
            float h2 = readlane_f(h, k + 2);
            float h3 = readlane_f(h, k + 3);
            a0 = fmaf(h0, wA[k], a0);
            a1 = fmaf(h1, wA[k + 1], a1);
            a2 = fmaf(h2, wA[k + 2], a2);
            a3 = fmaf(h3, wA[k + 3], a3);
            c0 = fmaf(h0, wB[k], c0);
            c1 = fmaf(h1, wB[k + 1], c1);
            c2 = fmaf(h2, wB[k + 2], c2);
            c3 = fmaf(h3, wB[k + 3], c3);
        }
        float g0 = (a0 + a1) + (a2 + a3);
        float g1 = (c0 + c1) + (c2 + c3);
        // lane<32: g0=i, g1=g ; lane>=32: g0=f, g1=o
        float fx = __shfl(g0, (lane & 31) + 32);
        float ox = __shfl(g1, (lane & 31) + 32);
        float si = sigm_f(g0);
        float sf = sigm_f(fx);
        float so = sigm_f(ox);
        cst = sf * cst + si * tanh_f(g1);
        float hn = so * tanh_f(cst);
        h = hn;
        if (lane < H_) hcat[((size_t)(b * T_) + t) * (2 * H_) + dir * H_ + lane] = hn;
        t = tn;
    }
}

// ---------------------------------------------------------------------------
// K5: temporal attention + LN + fc1 + fc2 -> out (B,3). grid B, block 256.
// ---------------------------------------------------------------------------
__global__ __launch_bounds__(256) void k_final(
    const float* __restrict__ hcat,
    const float* __restrict__ taW, const float* __restrict__ tab,
    const float* __restrict__ tav,
    const float* __restrict__ lng, const float* __restrict__ lnb,
    const float* __restrict__ w1, const float* __restrict__ b1,
    const float* __restrict__ w2, const float* __restrict__ b2,
    float* __restrict__ out) {
    int b = blockIdx.x;
    int t = threadIdx.x;
    __shared__ float Wl[64 * 64];
    __shared__ float al[T_];
    __shared__ float wred[4];
    __shared__ float ctxp[4][64];
    __shared__ float ctx[64];
    __shared__ float a1[32];
    for (int i = t; i < 4096; i += 256) Wl[i] = taW[i];
    float4 hr[16];
    const float4* hb = (const float4*)(hcat + ((size_t)b * T_ + t) * 64);
#pragma unroll
    for (int i = 0; i < 16; i++) hr[i] = hb[i];
    __syncthreads();
    float sc = 0.f;
    for (int j = 0; j < 64; j++) {
        float s = tab[j];
#pragma unroll
        for (int k4 = 0; k4 < 16; k4++) {
            float4 h4 = hr[k4];
            const float* wcol = &Wl[(4 * k4) * 64 + j];
            s += h4.x * wcol[0] + h4.y * wcol[64] + h4.z * wcol[128] + h4.w * wcol[192];
        }
        sc += tanhf(s) * tav[j];
    }
    sc *= (1.0f / 1.5f);
    int wave = t >> 6, lane = t & 63;
    float m = sc;
#pragma unroll
    for (int s_ = 1; s_ < 64; s_ <<= 1) m = fmaxf(m, __shfl_xor(m, s_));
    if (lane == 0) wred[wave] = m;
    __syncthreads();
    m = fmaxf(fmaxf(wred[0], wred[1]), fmaxf(wred[2], wred[3]));
    float e = __expf(sc - m);
    float ssum = e;
#pragma unroll
    for (int s_ = 1; s_ < 64; s_ <<= 1) ssum += __shfl_xor(ssum, s_);
    __syncthreads();
    if (lane == 0) wred[wave] = ssum;
    __syncthreads();
    float S = wred[0] + wred[1] + wred[2] + wred[3];
    al[t] = e / S;
    __syncthreads();
    // ctx partials: thread = (part = t>>6, o = t&63)
    {
        int o = t & 63, part = t >> 6;
        float cacc = 0.f;
        for (int tt = part * 64; tt < part * 64 + 64; tt++)
            cacc += al[tt] * hcat[((size_t)b * T_ + tt) * 64 + o];
        ctxp[part][o] = cacc;
    }
    __syncthreads();
    if (t < 64) {
        float ctxo = ctxp[0][t] + ctxp[1][t] + ctxp[2][t] + ctxp[3][t];
        float sv = ctxo, sq = ctxo * ctxo;
#pragma unroll
        for (int s_ = 1; s_ < 64; s_ <<= 1) {
            sv += __shfl_xor(sv, s_);
            sq += __shfl_xor(sq, s_);
        }
        float mu = sv * (1.f / 64.f);
        float var = sq * (1.f / 64.f) - mu * mu;
        ctx[t] = (ctxo - mu) / sqrtf(var + 1e-5f) * lng[t] + lnb[t];
    }
    __syncthreads();
    if (t < 32) {
        float s = b1[t];
        for (int k = 0; k < 64; k++) s += ctx[k] * w1[k * 32 + t];
        a1[t] = fmaxf(s, 0.f);
    }
    __syncthreads();
    if (t < 3) {
        float s = b2[t];
        for (int k = 0; k < 32; k++) s += a1[k] * w2[k * 3 + t];
        out[b * 3 + t] = s;
    }
}

// ---------------------------------------------------------------------------
extern "C" void kernel_launch(void* const* d_in, const int* in_sizes, int n_in,
                              void* d_out, int out_size, void* d_ws, size_t ws_size,
                              hipStream_t stream) {
    const float* x          = (const float*)d_in[0];
    const float* spectral_w = (const float*)d_in[1];
    const float* gat_W      = (const float*)d_in[2];
    const float* gat_a      = (const float*)d_in[3];
    const float* pool_w     = (const float*)d_in[4];
    const float* pool_b     = (const float*)d_in[5];
    const float* lstm_Wi_f  = (const float*)d_in[6];
    const float* lstm_Wh_f  = (const float*)d_in[7];
    const float* lstm_b_f   = (const float*)d_in[8];
    const float* lstm_Wi_r  = (const float*)d_in[9];
    const float* lstm_Wh_r  = (const float*)d_in[10];
    const float* lstm_b_r   = (const float*)d_in[11];
    const float* ta_W       = (const float*)d_in[12];
    const float* ta_b       = (const float*)d_in[13];
    const float* ta_v       = (const float*)d_in[14];
    const float* ln_g       = (const float*)d_in[15];
    const float* ln_b       = (const float*)d_in[16];
    const float* fc1_w      = (const float*)d_in[17];
    const float* fc1_b      = (const float*)d_in[18];
    const float* fc2_w      = (const float*)d_in[19];
    const float* fc2_b      = (const float*)d_in[20];
    float* out = (float*)d_out;

    float* ws = (float*)d_ws;
    float* sw    = ws + 0;                         // 8192
    float* A     = ws + 8192;                      // 65536
    unsigned long long* amask = (unsigned long long*)(ws + 73728);  // 1024 u64
    float* Wh    = ws + 75776;                     // 8388608
    float* s1    = ws + 8464384;                   // 262144
    float* s2    = ws + 8726528;                   // 262144
    float* hpool = ws + 8988672;                   // 131072
    float* gx    = ws + 9119744;                   // 1048576
    float* hcat  = ws + 10168320;                  // 262144

    hipMemsetAsync(A, 0, (size_t)C_ * C_ * B_ * sizeof(float), stream);
    k_sw<<<C_, 64, 0, stream>>>(spectral_w, sw);
    k_phase1<<<dim3(B_, T_ / TCP), 256, 0, stream>>>(x, sw, gat_W, gat_a, A, Wh, s1, s2);
    k_topk<<<B_, 64, 0, stream>>>(A, amask);
    k_gat<<<B_ * T_ / 4, 256, 0, stream>>>(Wh, s1, s2, amask, pool_w, pool_b, hpool);
    k_lstm_pre<<<2 * B_ * T_, 128, 0, stream>>>(hpool, lstm_Wi_f, lstm_b_f,
                                                lstm_Wi_r, lstm_b_r, gx);
    k_lstm_seq<<<2 * B_, 64, 0, stream>>>(gx, lstm_Wh_f, lstm_Wh_r, hcat);
    k_final<<<B_, 256, 0, stream>>>(hcat, ta_W, ta_b, ta_v, ln_g, ln_b,
                                    fc1_w, fc1_b, fc2_w, fc2_b, out);
}

// Round 4
// 447.013 us; speedup vs baseline: 1.3113x; 1.0157x over previous
//
#include <hip/hip_runtime.h>
#include <hip/hip_bf16.h>

// Dims
#define B_  16
#define T_  256
#define C_  64
#define F_  128
#define O_  32   // GO
#define H_  32
#define G4_ 128  // 4*H

typedef __attribute__((ext_vector_type(8))) short bfrag;
typedef __attribute__((ext_vector_type(4))) float f4acc;

__device__ __forceinline__ unsigned short f2bf(float v) {
    union { float f; unsigned u; } c; c.f = v;
    unsigned r = c.u + 0x7FFF + ((c.u >> 16) & 1);
    return (unsigned short)(r >> 16);
}
__device__ __forceinline__ float bf2f(unsigned short b) {
    union { float f; unsigned u; } c; c.u = ((unsigned)b) << 16; return c.f;
}
__device__ __forceinline__ float sigm_f(float x) {
    return __builtin_amdgcn_rcpf(1.f + __expf(-x));
}
__device__ __forceinline__ float tanh_f(float x) {
    float e = __expf(2.f * x);
    return 1.f - 2.f * __builtin_amdgcn_rcpf(e + 1.f);
}
__device__ __forceinline__ float readlane_f(float v, int l) {
    return __int_as_float(__builtin_amdgcn_readlane(__float_as_int(v), l));
}

// ---------------------------------------------------------------------------
// K0: softmax of spectral_w rows (64 rows of 128)
// ---------------------------------------------------------------------------
__global__ __launch_bounds__(64) void k_sw(const float* __restrict__ w,
                                           float* __restrict__ sw) {
    int c = blockIdx.x, lane = threadIdx.x;
    const float* row = w + c * F_;
    float v0 = row[lane], v1 = row[lane + 64];
    float m = fmaxf(v0, v1);
#pragma unroll
    for (int s = 1; s < 64; s <<= 1) m = fmaxf(m, __shfl_xor(m, s));
    float e0 = __expf(v0 - m), e1 = __expf(v1 - m);
    float s = e0 + e1;
#pragma unroll
    for (int s_ = 1; s_ < 64; s_ <<= 1) s += __shfl_xor(s, s_);
    sw[c * F_ + lane] = e0 / s;
    sw[c * F_ + lane + 64] = e1 / s;
}

// ---------------------------------------------------------------------------
// K1: MFMA phase1. split-bf16 (hi/lo) Hn planes in LDS.
// grid (B, T/TCP), block 256.
// ---------------------------------------------------------------------------
#define TCP 4
#define PSTR 136   // bf16 elements per row (272 B): 16B-aligned, bank-uniform

#define MFMA16(a, b, c) __builtin_amdgcn_mfma_f32_16x16x32_bf16(a, b, c, 0, 0, 0)

__global__ __launch_bounds__(256) void k_phase1(
    const float* __restrict__ x, const float* __restrict__ sw,
    const float* __restrict__ gat_W, const float* __restrict__ gat_a,
    float* __restrict__ A, float* __restrict__ Wh,
    float* __restrict__ s1, float* __restrict__ s2) {
    const int b = blockIdx.x, tc = blockIdx.y, tid = threadIdx.x;
    const int wv = tid >> 6, lane = tid & 63;
    const int quad = lane >> 4, l16 = lane & 15;

    __shared__ unsigned short hhi[64 * PSTR];
    __shared__ unsigned short hlo[64 * PSTR];
    __shared__ float nrm[64];
    __shared__ float s1p[2][64], s2p[2][64];

    // sw regs (same (c,f) slice every t)
    float4 swr[8];
    {
        const float4* sw4 = (const float4*)sw;
#pragma unroll
        for (int i = 0; i < 8; i++) swr[i] = sw4[tid + 256 * i];
    }

    const int rt0 = (wv >> 1) * 2;  // row-tile base {0,2}
    const int ct0 = (wv & 1) * 2;   // col-tile base {0,2}
    const int jW = wv & 1;          // Wh col-tile

    // W fragments (hi/lo) for this wave's jW, ksteps 0..3, held in regs
    bfrag wfh[4], wfl[4];
    {
        const int n = l16 + 16 * jW;
#pragma unroll
        for (int k = 0; k < 4; k++) {
            union { unsigned short u[8]; bfrag v; } Hu, Lu;
#pragma unroll
            for (int u = 0; u < 8; u++) {
                float v = gat_W[(32 * k + quad * 8 + u) * O_ + n];
                unsigned short hb = f2bf(v);
                Hu.u[u] = hb;
                Lu.u[u] = f2bf(v - bf2f(hb));
            }
            wfh[k] = Hu.v;
            wfl[k] = Lu.v;
        }
    }
    const float ga1 = gat_a[l16 + 16 * jW];
    const float ga2 = gat_a[O_ + l16 + 16 * jW];

    f4acc accA[2][2];
#pragma unroll
    for (int i = 0; i < 2; i++)
#pragma unroll
        for (int j = 0; j < 2; j++) accA[i][j] = (f4acc){0.f, 0.f, 0.f, 0.f};

    for (int tt = 0; tt < TCP; ++tt) {
        const int t = tc * TCP + tt;
        const float4* xg = (const float4*)(x + ((size_t)(b * T_ + t) << 13));
        float4 xr[8];
#pragma unroll
        for (int i = 0; i < 8; i++) xr[i] = xg[tid + 256 * i];

        __syncthreads();  // (a) prev-t frag reads done before plane overwrite

        float invn_[8];
#pragma unroll
        for (int i = 0; i < 8; i++) {
            float4 v = xr[i], s = swr[i];
            v.x *= s.x; v.y *= s.y; v.z *= s.z; v.w *= s.w;
            xr[i] = v;
            float ss = v.x * v.x + v.y * v.y + v.z * v.z + v.w * v.w;
#pragma unroll
            for (int d = 1; d < 32; d <<= 1) ss += __shfl_xor(ss, d);
            float nv = sqrtf(ss) + 1e-8f;
            invn_[i] = 1.0f / nv;
            if ((tid & 31) == 0) nrm[(tid >> 5) + 8 * i] = nv;
        }
        // split + write planes: row c=(tid>>5)+8i, f = 4*(tid&31)
#pragma unroll
        for (int i = 0; i < 8; i++) {
            int c = (tid >> 5) + 8 * i;
            float4 v = xr[i];
            float iv = invn_[i];
            float a0 = v.x * iv, a1 = v.y * iv, a2 = v.z * iv, a3 = v.w * iv;
            union { unsigned short u[4]; unsigned long long q; } Hq, Lq;
            unsigned short h0 = f2bf(a0), h1 = f2bf(a1), h2 = f2bf(a2), h3 = f2bf(a3);
            Hq.u[0] = h0; Hq.u[1] = h1; Hq.u[2] = h2; Hq.u[3] = h3;
            Lq.u[0] = f2bf(a0 - bf2f(h0));
            Lq.u[1] = f2bf(a1 - bf2f(h1));
            Lq.u[2] = f2bf(a2 - bf2f(h2));
            Lq.u[3] = f2bf(a3 - bf2f(h3));
            int off = c * PSTR + 4 * (tid & 31);
            *(unsigned long long*)&hhi[off] = Hq.q;
            *(unsigned long long*)&hlo[off] = Lq.q;
        }
        __syncthreads();  // (b) planes ready

        f4acc accW0 = (f4acc){0.f, 0.f, 0.f, 0.f};
        f4acc accW1 = (f4acc){0.f, 0.f, 0.f, 0.f};
#pragma unroll
        for (int k = 0; k < 4; k++) {
            const int ko = 32 * k + 8 * quad;
            bfrag r0h = *(const bfrag*)&hhi[(rt0 * 16 + l16) * PSTR + ko];
            bfrag r0l = *(const bfrag*)&hlo[(rt0 * 16 + l16) * PSTR + ko];
            bfrag r1h = *(const bfrag*)&hhi[((rt0 + 1) * 16 + l16) * PSTR + ko];
            bfrag r1l = *(const bfrag*)&hlo[((rt0 + 1) * 16 + l16) * PSTR + ko];
            bfrag c0h = *(const bfrag*)&hhi[(ct0 * 16 + l16) * PSTR + ko];
            bfrag c0l = *(const bfrag*)&hlo[(ct0 * 16 + l16) * PSTR + ko];
            bfrag c1h = *(const bfrag*)&hhi[((ct0 + 1) * 16 + l16) * PSTR + ko];
            bfrag c1l = *(const bfrag*)&hlo[((ct0 + 1) * 16 + l16) * PSTR + ko];
            // A quadrant: 4 tiles x 3 products
            accA[0][0] = MFMA16(r0h, c0h, accA[0][0]);
            accA[0][0] = MFMA16(r0h, c0l, accA[0][0]);
            accA[0][0] = MFMA16(r0l, c0h, accA[0][0]);
            accA[0][1] = MFMA16(r0h, c1h, accA[0][1]);
            accA[0][1] = MFMA16(r0h, c1l, accA[0][1]);
            accA[0][1] = MFMA16(r0l, c1h, accA[0][1]);
            accA[1][0] = MFMA16(r1h, c0h, accA[1][0]);
            accA[1][0] = MFMA16(r1h, c0l, accA[1][0]);
            accA[1][0] = MFMA16(r1l, c0h, accA[1][0]);
            accA[1][1] = MFMA16(r1h, c1h, accA[1][1]);
            accA[1][1] = MFMA16(r1h, c1l, accA[1][1]);
            accA[1][1] = MFMA16(r1l, c1h, accA[1][1]);
            // Wh tiles (rows rt0, rt0+1; col jW), W frags in regs
            accW0 = MFMA16(r0h, wfh[k], accW0);
            accW0 = MFMA16(r0h, wfl[k], accW0);
            accW0 = MFMA16(r0l, wfh[k], accW0);
            accW1 = MFMA16(r1h, wfh[k], accW1);
            accW1 = MFMA16(r1h, wfl[k], accW1);
            accW1 = MFMA16(r1l, wfh[k], accW1);
        }
        // epilogue: scale rows by nrm, write Wh, reduce s1/s2 per row
        float* whout = Wh + (size_t)(b * T_ + t) * (C_ * O_);
#pragma unroll
        for (int i2 = 0; i2 < 2; i2++) {
            f4acc aw = i2 ? accW1 : accW0;
#pragma unroll
            for (int r = 0; r < 4; r++) {
                int row = (rt0 + i2) * 16 + quad * 4 + r;
                float val = aw[r] * nrm[row];
                whout[row * O_ + l16 + 16 * jW] = val;
                float v1 = val * ga1, v2 = val * ga2;
#pragma unroll
                for (int d = 1; d < 16; d <<= 1) {
                    v1 += __shfl_xor(v1, d);
                    v2 += __shfl_xor(v2, d);
                }
                if (l16 == 0) { s1p[jW][row] = v1; s2p[jW][row] = v2; }
            }
        }
        __syncthreads();  // (c) s1p/s2p ready
        if (tid < 64) {
            s1[(b * T_ + t) * C_ + tid] = s1p[0][tid] + s1p[1][tid];
            s2[(b * T_ + t) * C_ + tid] = s2p[0][tid] + s2p[1][tid];
        }
    }
    // block-end: quadrants disjoint -> direct atomicAdd
#pragma unroll
    for (int i2 = 0; i2 < 2; i2++)
#pragma unroll
        for (int j2 = 0; j2 < 2; j2++)
#pragma unroll
            for (int r = 0; r < 4; r++) {
                int row = (rt0 + i2) * 16 + quad * 4 + r;
                int col = (ct0 + j2) * 16 + l16;
                atomicAdd(&A[b * (C_ * C_) + row * C_ + col], accA[i2][j2][r]);
            }
}

// ---------------------------------------------------------------------------
// K2: top-4 selection + symmetrize -> amask bitmask per (b,c). grid B, block 64
// ---------------------------------------------------------------------------
__global__ __launch_bounds__(64) void k_topk(const float* __restrict__ A,
                                             unsigned long long* __restrict__ amask) {
    int b = blockIdx.x;
    int c = threadIdx.x;
    __shared__ unsigned long long tk[C_];
    const float* row = A + b * (C_ * C_) + c * C_;
    unsigned long long sel = 0ULL;
    for (int r = 0; r < 4; r++) {
        float best = -1e30f;
        int bi = 0;
        for (int d = 0; d < C_; d++) {
            if (sel & (1ULL << d)) continue;
            float v = row[d];
            if (v > best) { best = v; bi = d; }
        }
        sel |= (1ULL << bi);
    }
    unsigned long long t = sel & ~(1ULL << c);
    tk[c] = t;
    __syncthreads();
    unsigned long long sym = t;
    for (int d = 0; d < C_; d++)
        if ((tk[d] >> c) & 1ULL) sym |= (1ULL << d);
    unsigned long long m = (1ULL << c);
    unsigned long long s2 = sym;
    while (s2) {
        int d = __ffsll(s2) - 1;
        s2 &= s2 - 1;
        if (row[d] > 0.f) m |= (1ULL << d);
    }
    amask[b * C_ + c] = m;
}

// ---------------------------------------------------------------------------
// K3: GAT attention + relu + pooling. block 256 = 4 waves = 4 t's. grid B*T/4.
// ---------------------------------------------------------------------------
__global__ __launch_bounds__(256) void k_gat(
    const float* __restrict__ Wh, const float* __restrict__ s1,
    const float* __restrict__ s2, const unsigned long long* __restrict__ amask,
    const float* __restrict__ pool_w, const float* __restrict__ pool_b,
    float* __restrict__ hout) {
    int tg = blockIdx.x;
    int wv = threadIdx.x >> 6, c = threadIdx.x & 63;
    int bt = tg * 4 + wv;
    int b = bt >> 8;
    __shared__ float buf[4][C_][33];
    __shared__ float s2s[4][C_];

    s2s[wv][c] = s2[bt * C_ + c];
    float s1c = s1[bt * C_ + c];
    unsigned long long m = amask[b * C_ + c];
    __syncthreads();

    float mx = -1e30f;
    unsigned long long mm = m;
    while (mm) {
        int d = __ffsll(mm) - 1; mm &= mm - 1;
        float v = s1c + s2s[wv][d];
        v = v > 0.f ? v : 0.2f * v;
        mx = fmaxf(mx, v);
    }
    float ssum = 0.f;
    mm = m;
    while (mm) {
        int d = __ffsll(mm) - 1; mm &= mm - 1;
        float v = s1c + s2s[wv][d];
        v = v > 0.f ? v : 0.2f * v;
        ssum += __expf(v - mx);
    }
    float inv = 1.0f / ssum;
    float g[O_];
#pragma unroll
    for (int i = 0; i < O_; i++) g[i] = 0.f;
    mm = m;
    while (mm) {
        int d = __ffsll(mm) - 1; mm &= mm - 1;
        float v = s1c + s2s[wv][d];
        v = v > 0.f ? v : 0.2f * v;
        float a = __expf(v - mx);
        const float4* wr = (const float4*)(Wh + (size_t)bt * (C_ * O_) + d * O_);
#pragma unroll
        for (int q = 0; q < 8; q++) {
            float4 w4 = wr[q];
            g[4 * q + 0] += a * w4.x;
            g[4 * q + 1] += a * w4.y;
            g[4 * q + 2] += a * w4.z;
            g[4 * q + 3] += a * w4.w;
        }
    }
    float lg = pool_b[0];
#pragma unroll
    for (int i = 0; i < O_; i++) {
        g[i] = fmaxf(g[i] * inv, 0.f);
        lg += g[i] * pool_w[i];
    }
    float wmx = lg;
#pragma unroll
    for (int s = 1; s < 64; s <<= 1) wmx = fmaxf(wmx, __shfl_xor(wmx, s));
    float we = __expf(lg - wmx);
    float wsum = we;
#pragma unroll
    for (int s = 1; s < 64; s <<= 1) wsum += __shfl_xor(wsum, s);
    float wcf = we / wsum;
#pragma unroll
    for (int i = 0; i < O_; i++) buf[wv][c][i] = g[i] * wcf;
    __syncthreads();
    {
        int wt = threadIdx.x >> 6, o = threadIdx.x & 31, hf = (threadIdx.x >> 5) & 1;
        float sacc = 0.f;
#pragma unroll 8
        for (int d = hf * 32; d < hf * 32 + 32; d++) sacc += buf[wt][d][o];
        sacc += __shfl_xor(sacc, 32);
        if (hf == 0) hout[(tg * 4 + wt) * O_ + o] = sacc;
    }
}

// ---------------------------------------------------------------------------
// K4a: LSTM input projection gx = h @ Wi + b. grid 2*B*T, block 128
// ---------------------------------------------------------------------------
__global__ __launch_bounds__(128) void k_lstm_pre(
    const float* __restrict__ hin,
    const float* __restrict__ Wi_f, const float* __restrict__ b_f,
    const float* __restrict__ Wi_r, const float* __restrict__ b_r,
    float* __restrict__ gx) {
    int id = blockIdx.x;
    int dir = id >> 12;
    int bt = id & 4095;
    const float* Wi = dir ? Wi_r : Wi_f;
    const float* bb = dir ? b_r : b_f;
    int g = threadIdx.x;
    __shared__ float hs[H_];
    if (g < H_) hs[g] = hin[bt * O_ + g];
    __syncthreads();
    float acc = bb[g];
#pragma unroll
    for (int k = 0; k < H_; k++) acc += hs[k] * Wi[k * G4_ + g];
    gx[((size_t)dir * 4096 + bt) * G4_ + g] = acc;
}

// ---------------------------------------------------------------------------
// K4b: LSTM recurrence — single wave per (dir,b).
// Weights in 32 NAMED float2 vars (never address-taken -> guaranteed VGPRs;
// arrays fail SROA since it runs before unroll -> round-3's scratch reloads).
// ww_k = (W[k][lane], W[k][lane+64]):
//   lanes 0..31:  g0 = gate i, g1 = gate g
//   lanes 32..63: g0 = gate f, g1 = gate o
// Nonlinearity applied BEFORE cross-half shuffle; tanh via 2*sigm(2x)-1 keeps
// both halves on the same instruction stream (no divergence).
// grid 2*B, block 64.
// ---------------------------------------------------------------------------
#define WW(k) float2 ww##k = make_float2(Wd[(k) * G4_ + lane], Wd[(k) * G4_ + lane + 64]);
#define KST(k, Aq) { float hk = readlane_f(h, k); \
    Aq.x = fmaf(hk, ww##k.x, Aq.x); Aq.y = fmaf(hk, ww##k.y, Aq.y); }

__global__ __launch_bounds__(64, 1) void k_lstm_seq(
    const float* __restrict__ gx,
    const float* __restrict__ Whf, const float* __restrict__ Whr,
    float* __restrict__ hcat) {
    int dir = blockIdx.x & 1, b = blockIdx.x >> 1;
    int lane = threadIdx.x;
    const float* Wd = dir ? Whr : Whf;
    WW(0) WW(1) WW(2) WW(3) WW(4) WW(5) WW(6) WW(7)
    WW(8) WW(9) WW(10) WW(11) WW(12) WW(13) WW(14) WW(15)
    WW(16) WW(17) WW(18) WW(19) WW(20) WW(21) WW(22) WW(23)
    WW(24) WW(25) WW(26) WW(27) WW(28) WW(29) WW(30) WW(31)

    const float* gxb = gx + ((size_t)dir * 4096 + b * T_) * G4_;
    float h = 0.f, cst = 0.f;
    const int dt = dir ? -1 : 1;
    int t = dir ? (T_ - 1) : 0;
    float g0n = gxb[t * G4_ + lane], g1n = gxb[t * G4_ + lane + 64];
    const float half_sel = (lane < 32) ? 2.f : 1.f;
    for (int s = 0; s < T_; s++) {
        int tn = t + dt;
        float2 A0 = make_float2(g0n, g1n);
        float2 A1 = make_float2(0.f, 0.f);
        float2 A2 = make_float2(0.f, 0.f);
        float2 A3 = make_float2(0.f, 0.f);
        if (s < T_ - 1) {
            g0n = gxb[tn * G4_ + lane];
            g1n = gxb[tn * G4_ + lane + 64];
        }
        KST(0, A0)  KST(1, A1)  KST(2, A2)  KST(3, A3)
        KST(4, A0)  KST(5, A1)  KST(6, A2)  KST(7, A3)
        KST(8, A0)  KST(9, A1)  KST(10, A2) KST(11, A3)
        KST(12, A0) KST(13, A1) KST(14, A2) KST(15, A3)
        KST(16, A0) KST(17, A1) KST(18, A2) KST(19, A3)
        KST(20, A0) KST(21, A1) KST(22, A2) KST(23, A3)
        KST(24, A0) KST(25, A1) KST(26, A2) KST(27, A3)
        KST(28, A0) KST(29, A1) KST(30, A2) KST(31, A3)
        float g0 = (A0.x + A1.x) + (A2.x + A3.x);
        float g1 = (A0.y + A1.y) + (A2.y + A3.y);
        // lanes<32: sA=sigm(i), sB=tanh(g)=2*sigm(2g)-1 ; lanes>=32: sA=sigm(f), sB=sigm(o)
        float sA = sigm_f(g0);
        float u = sigm_f(half_sel * g1);
        float sB = (lane < 32) ? fmaf(2.f, u, -1.f) : u;
        float sf = __shfl(sA, (lane & 31) + 32);
        float so = __shfl(sB, (lane & 31) + 32);
        cst = fmaf(sf, cst, sA * sB);
        float hn = so * tanh_f(cst);
        h = hn;
        if (lane < H_) hcat[((size_t)(b * T_) + t) * (2 * H_) + dir * H_ + lane] = hn;
        t = tn;
    }
}

// ---------------------------------------------------------------------------
// K5: temporal attention + LN + fc1 + fc2 -> out (B,3). grid B, block 256.
// ---------------------------------------------------------------------------
__global__ __launch_bounds__(256) void k_final(
    const float* __restrict__ hcat,
    const float* __restrict__ taW, const float* __restrict__ tab,
    const float* __restrict__ tav,
    const float* __restrict__ lng, const float* __restrict__ lnb,
    const float* __restrict__ w1, const float* __restrict__ b1,
    const float* __restrict__ w2, const float* __restrict__ b2,
    float* __restrict__ out) {
    int b = blockIdx.x;
    int t = threadIdx.x;
    __shared__ float Wl[64 * 64];
    __shared__ float al[T_];
    __shared__ float wred[4];
    __shared__ float ctxp[4][64];
    __shared__ float ctx[64];
    __shared__ float a1[32];
    for (int i = t; i < 4096; i += 256) Wl[i] = taW[i];
    float4 hr[16];
    const float4* hb = (const float4*)(hcat + ((size_t)b * T_ + t) * 64);
#pragma unroll
    for (int i = 0; i < 16; i++) hr[i] = hb[i];
    __syncthreads();
    float sc = 0.f;
    for (int j = 0; j < 64; j++) {
        float s = tab[j];
#pragma unroll
        for (int k4 = 0; k4 < 16; k4++) {
            float4 h4 = hr[k4];
            const float* wcol = &Wl[(4 * k4) * 64 + j];
            s += h4.x * wcol[0] + h4.y * wcol[64] + h4.z * wcol[128] + h4.w * wcol[192];
        }
        sc += tanhf(s) * tav[j];
    }
    sc *= (1.0f / 1.5f);
    int wave = t >> 6, lane = t & 63;
    float m = sc;
#pragma unroll
    for (int s_ = 1; s_ < 64; s_ <<= 1) m = fmaxf(m, __shfl_xor(m, s_));
    if (lane == 0) wred[wave] = m;
    __syncthreads();
    m = fmaxf(fmaxf(wred[0], wred[1]), fmaxf(wred[2], wred[3]));
    float e = __expf(sc - m);
    float ssum = e;
#pragma unroll
    for (int s_ = 1; s_ < 64; s_ <<= 1) ssum += __shfl_xor(ssum, s_);
    __syncthreads();
    if (lane == 0) wred[wave] = ssum;
    __syncthreads();
    float S = wred[0] + wred[1] + wred[2] + wred[3];
    al[t] = e / S;
    __syncthreads();
    // ctx partials: thread = (part = t>>6, o = t&63)
    {
        int o = t & 63, part = t >> 6;
        float cacc = 0.f;
        for (int tt = part * 64; tt < part * 64 + 64; tt++)
            cacc += al[tt] * hcat[((size_t)b * T_ + tt) * 64 + o];
        ctxp[part][o] = cacc;
    }
    __syncthreads();
    if (t < 64) {
        float ctxo = ctxp[0][t] + ctxp[1][t] + ctxp[2][t] + ctxp[3][t];
        float sv = ctxo, sq = ctxo * ctxo;
#pragma unroll
        for (int s_ = 1; s_ < 64; s_ <<= 1) {
            sv += __shfl_xor(sv, s_);
            sq += __shfl_xor(sq, s_);
        }
        float mu = sv * (1.f / 64.f);
        float var = sq * (1.f / 64.f) - mu * mu;
        ctx[t] = (ctxo - mu) / sqrtf(var + 1e-5f) * lng[t] + lnb[t];
    }
    __syncthreads();
    if (t < 32) {
        float s = b1[t];
        for (int k = 0; k < 64; k++) s += ctx[k] * w1[k * 32 + t];
        a1[t] = fmaxf(s, 0.f);
    }
    __syncthreads();
    if (t < 3) {
        float s = b2[t];
        for (int k = 0; k < 32; k++) s += a1[k] * w2[k * 3 + t];
        out[b * 3 + t] = s;
    }
}

// ---------------------------------------------------------------------------
extern "C" void kernel_launch(void* const* d_in, const int* in_sizes, int n_in,
                              void* d_out, int out_size, void* d_ws, size_t ws_size,
                              hipStream_t stream) {
    const float* x          = (const float*)d_in[0];
    const float* spectral_w = (const float*)d_in[1];
    const float* gat_W      = (const float*)d_in[2];
    const float* gat_a      = (const float*)d_in[3];
    const float* pool_w     = (const float*)d_in[4];
    const float* pool_b     = (const float*)d_in[5];
    const float* lstm_Wi_f  = (const float*)d_in[6];
    const float* lstm_Wh_f  = (const float*)d_in[7];
    const float* lstm_b_f   = (const float*)d_in[8];
    const float* lstm_Wi_r  = (const float*)d_in[9];
    const float* lstm_Wh_r  = (const float*)d_in[10];
    const float* lstm_b_r   = (const float*)d_in[11];
    const float* ta_W       = (const float*)d_in[12];
    const float* ta_b       = (const float*)d_in[13];
    const float* ta_v       = (const float*)d_in[14];
    const float* ln_g       = (const float*)d_in[15];
    const float* ln_b       = (const float*)d_in[16];
    const float* fc1_w      = (const float*)d_in[17];
    const float* fc1_b      = (const float*)d_in[18];
    const float* fc2_w      = (const float*)d_in[19];
    const float* fc2_b      = (const float*)d_in[20];
    float* out = (float*)d_out;

    float* ws = (float*)d_ws;
    float* sw    = ws + 0;                         // 8192
    float* A     = ws + 8192;                      // 65536
    unsigned long long* amask = (unsigned long long*)(ws + 73728);  // 1024 u64
    float* Wh    = ws + 75776;                     // 8388608
    float* s1    = ws + 8464384;                   // 262144
    float* s2    = ws + 8726528;                   // 262144
    float* hpool = ws + 8988672;                   // 131072
    float* gx    = ws + 9119744;                   // 1048576
    float* hcat  = ws + 10168320;                  // 262144

    hipMemsetAsync(A, 0, (size_t)C_ * C_ * B_ * sizeof(float), stream);
    k_sw<<<C_, 64, 0, stream>>>(spectral_w, sw);
    k_phase1<<<dim3(B_, T_ / TCP), 256, 0, stream>>>(x, sw, gat_W, gat_a, A, Wh, s1, s2);
    k_topk<<<B_, 64, 0, stream>>>(A, amask);
    k_gat<<<B_ * T_ / 4, 256, 0, stream>>>(Wh, s1, s2, amask, pool_w, pool_b, hpool);
    k_lstm_pre<<<2 * B_ * T_, 128, 0, stream>>>(hpool, lstm_Wi_f, lstm_b_f,
                                                lstm_Wi_r, lstm_b_r, gx);
    k_lstm_seq<<<2 * B_, 64, 0, stream>>>(gx, lstm_Wh_f, lstm_Wh_r, hcat);
    k_final<<<B_, 256, 0, stream>>>(hcat, ta_W, ta_b, ta_v, ln_g, ln_b,
                                    fc1_w, fc1_b, fc2_w, fc2_b, out);
}

// Round 5
// 440.698 us; speedup vs baseline: 1.3301x; 1.0143x over previous
//
#include <hip/hip_runtime.h>
#include <hip/hip_bf16.h>

// Dims
#define B_  16
#define T_  256
#define C_  64
#define F_  128
#define O_  32   // GO
#define H_  32
#define G4_ 128  // 4*H

typedef __attribute__((ext_vector_type(8))) short bfrag;
typedef __attribute__((ext_vector_type(4))) float f4acc;

__device__ __forceinline__ unsigned short f2bf(float v) {
    union { float f; unsigned u; } c; c.f = v;
    unsigned r = c.u + 0x7FFF + ((c.u >> 16) & 1);
    return (unsigned short)(r >> 16);
}
__device__ __forceinline__ float bf2f(unsigned short b) {
    union { float f; unsigned u; } c; c.u = ((unsigned)b) << 16; return c.f;
}
__device__ __forceinline__ float sigm_f(float x) {
    return __builtin_amdgcn_rcpf(1.f + __expf(-x));
}
__device__ __forceinline__ float tanh_f(float x) {
    float e = __expf(2.f * x);
    return 1.f - 2.f * __builtin_amdgcn_rcpf(e + 1.f);
}
__device__ __forceinline__ float readlane_f(float v, int l) {
    return __int_as_float(__builtin_amdgcn_readlane(__float_as_int(v), l));
}

// ---------------------------------------------------------------------------
// K0: softmax of spectral_w rows (64 rows of 128)
// ---------------------------------------------------------------------------
__global__ __launch_bounds__(64) void k_sw(const float* __restrict__ w,
                                           float* __restrict__ sw) {
    int c = blockIdx.x, lane = threadIdx.x;
    const float* row = w + c * F_;
    float v0 = row[lane], v1 = row[lane + 64];
    float m = fmaxf(v0, v1);
#pragma unroll
    for (int s = 1; s < 64; s <<= 1) m = fmaxf(m, __shfl_xor(m, s));
    float e0 = __expf(v0 - m), e1 = __expf(v1 - m);
    float s = e0 + e1;
#pragma unroll
    for (int s_ = 1; s_ < 64; s_ <<= 1) s += __shfl_xor(s, s_);
    sw[c * F_ + lane] = e0 / s;
    sw[c * F_ + lane + 64] = e1 / s;
}

// ---------------------------------------------------------------------------
// K1: MFMA phase1. split-bf16 (hi/lo) Hn planes in LDS.
// grid (B, T/TCP), block 256.
// ---------------------------------------------------------------------------
#define TCP 4
#define PSTR 136   // bf16 elements per row (272 B): 16B-aligned, bank-uniform

#define MFMA16(a, b, c) __builtin_amdgcn_mfma_f32_16x16x32_bf16(a, b, c, 0, 0, 0)

__global__ __launch_bounds__(256) void k_phase1(
    const float* __restrict__ x, const float* __restrict__ sw,
    const float* __restrict__ gat_W, const float* __restrict__ gat_a,
    float* __restrict__ A, float* __restrict__ Wh,
    float* __restrict__ s1, float* __restrict__ s2) {
    const int b = blockIdx.x, tc = blockIdx.y, tid = threadIdx.x;
    const int wv = tid >> 6, lane = tid & 63;
    const int quad = lane >> 4, l16 = lane & 15;

    __shared__ unsigned short hhi[64 * PSTR];
    __shared__ unsigned short hlo[64 * PSTR];
    __shared__ float nrm[64];
    __shared__ float s1p[2][64], s2p[2][64];

    // sw regs (same (c,f) slice every t)
    float4 swr[8];
    {
        const float4* sw4 = (const float4*)sw;
#pragma unroll
        for (int i = 0; i < 8; i++) swr[i] = sw4[tid + 256 * i];
    }

    const int rt0 = (wv >> 1) * 2;  // row-tile base {0,2}
    const int ct0 = (wv & 1) * 2;   // col-tile base {0,2}
    const int jW = wv & 1;          // Wh col-tile

    // W fragments (hi/lo) for this wave's jW, ksteps 0..3, held in regs
    bfrag wfh[4], wfl[4];
    {
        const int n = l16 + 16 * jW;
#pragma unroll
        for (int k = 0; k < 4; k++) {
            union { unsigned short u[8]; bfrag v; } Hu, Lu;
#pragma unroll
            for (int u = 0; u < 8; u++) {
                float v = gat_W[(32 * k + quad * 8 + u) * O_ + n];
                unsigned short hb = f2bf(v);
                Hu.u[u] = hb;
                Lu.u[u] = f2bf(v - bf2f(hb));
            }
            wfh[k] = Hu.v;
            wfl[k] = Lu.v;
        }
    }
    const float ga1 = gat_a[l16 + 16 * jW];
    const float ga2 = gat_a[O_ + l16 + 16 * jW];

    f4acc accA[2][2];
#pragma unroll
    for (int i = 0; i < 2; i++)
#pragma unroll
        for (int j = 0; j < 2; j++) accA[i][j] = (f4acc){0.f, 0.f, 0.f, 0.f};

    for (int tt = 0; tt < TCP; ++tt) {
        const int t = tc * TCP + tt;
        const float4* xg = (const float4*)(x + ((size_t)(b * T_ + t) << 13));
        float4 xr[8];
#pragma unroll
        for (int i = 0; i < 8; i++) xr[i] = xg[tid + 256 * i];

        __syncthreads();  // (a) prev-t frag reads done before plane overwrite

        float invn_[8];
#pragma unroll
        for (int i = 0; i < 8; i++) {
            float4 v = xr[i], s = swr[i];
            v.x *= s.x; v.y *= s.y; v.z *= s.z; v.w *= s.w;
            xr[i] = v;
            float ss = v.x * v.x + v.y * v.y + v.z * v.z + v.w * v.w;
#pragma unroll
            for (int d = 1; d < 32; d <<= 1) ss += __shfl_xor(ss, d);
            float nv = sqrtf(ss) + 1e-8f;
            invn_[i] = 1.0f / nv;
            if ((tid & 31) == 0) nrm[(tid >> 5) + 8 * i] = nv;
        }
        // split + write planes: row c=(tid>>5)+8i, f = 4*(tid&31)
#pragma unroll
        for (int i = 0; i < 8; i++) {
            int c = (tid >> 5) + 8 * i;
            float4 v = xr[i];
            float iv = invn_[i];
            float a0 = v.x * iv, a1 = v.y * iv, a2 = v.z * iv, a3 = v.w * iv;
            union { unsigned short u[4]; unsigned long long q; } Hq, Lq;
            unsigned short h0 = f2bf(a0), h1 = f2bf(a1), h2 = f2bf(a2), h3 = f2bf(a3);
            Hq.u[0] = h0; Hq.u[1] = h1; Hq.u[2] = h2; Hq.u[3] = h3;
            Lq.u[0] = f2bf(a0 - bf2f(h0));
            Lq.u[1] = f2bf(a1 - bf2f(h1));
            Lq.u[2] = f2bf(a2 - bf2f(h2));
            Lq.u[3] = f2bf(a3 - bf2f(h3));
            int off = c * PSTR + 4 * (tid & 31);
            *(unsigned long long*)&hhi[off] = Hq.q;
            *(unsigned long long*)&hlo[off] = Lq.q;
        }
        __syncthreads();  // (b) planes ready

        f4acc accW0 = (f4acc){0.f, 0.f, 0.f, 0.f};
        f4acc accW1 = (f4acc){0.f, 0.f, 0.f, 0.f};
#pragma unroll
        for (int k = 0; k < 4; k++) {
            const int ko = 32 * k + 8 * quad;
            bfrag r0h = *(const bfrag*)&hhi[(rt0 * 16 + l16) * PSTR + ko];
            bfrag r0l = *(const bfrag*)&hlo[(rt0 * 16 + l16) * PSTR + ko];
            bfrag r1h = *(const bfrag*)&hhi[((rt0 + 1) * 16 + l16) * PSTR + ko];
            bfrag r1l = *(const bfrag*)&hlo[((rt0 + 1) * 16 + l16) * PSTR + ko];
            bfrag c0h = *(const bfrag*)&hhi[(ct0 * 16 + l16) * PSTR + ko];
            bfrag c0l = *(const bfrag*)&hlo[(ct0 * 16 + l16) * PSTR + ko];
            bfrag c1h = *(const bfrag*)&hhi[((ct0 + 1) * 16 + l16) * PSTR + ko];
            bfrag c1l = *(const bfrag*)&hlo[((ct0 + 1) * 16 + l16) * PSTR + ko];
            // A quadrant: 4 tiles x 3 products
            accA[0][0] = MFMA16(r0h, c0h, accA[0][0]);
            accA[0][0] = MFMA16(r0h, c0l, accA[0][0]);
            accA[0][0] = MFMA16(r0l, c0h, accA[0][0]);
            accA[0][1] = MFMA16(r0h, c1h, accA[0][1]);
            accA[0][1] = MFMA16(r0h, c1l, accA[0][1]);
            accA[0][1] = MFMA16(r0l, c1h, accA[0][1]);
            accA[1][0] = MFMA16(r1h, c0h, accA[1][0]);
            accA[1][0] = MFMA16(r1h, c0l, accA[1][0]);
            accA[1][0] = MFMA16(r1l, c0h, accA[1][0]);
            accA[1][1] = MFMA16(r1h, c1h, accA[1][1]);
            accA[1][1] = MFMA16(r1h, c1l, accA[1][1]);
            accA[1][1] = MFMA16(r1l, c1h, accA[1][1]);
            // Wh tiles (rows rt0, rt0+1; col jW), W frags in regs
            accW0 = MFMA16(r0h, wfh[k], accW0);
            accW0 = MFMA16(r0h, wfl[k], accW0);
            accW0 = MFMA16(r0l, wfh[k], accW0);
            accW1 = MFMA16(r1h, wfh[k], accW1);
            accW1 = MFMA16(r1h, wfl[k], accW1);
            accW1 = MFMA16(r1l, wfh[k], accW1);
        }
        // epilogue: scale rows by nrm, write Wh, reduce s1/s2 per row
        float* whout = Wh + (size_t)(b * T_ + t) * (C_ * O_);
#pragma unroll
        for (int i2 = 0; i2 < 2; i2++) {
            f4acc aw = i2 ? accW1 : accW0;
#pragma unroll
            for (int r = 0; r < 4; r++) {
                int row = (rt0 + i2) * 16 + quad * 4 + r;
                float val = aw[r] * nrm[row];
                whout[row * O_ + l16 + 16 * jW] = val;
                float v1 = val * ga1, v2 = val * ga2;
#pragma unroll
                for (int d = 1; d < 16; d <<= 1) {
                    v1 += __shfl_xor(v1, d);
                    v2 += __shfl_xor(v2, d);
                }
                if (l16 == 0) { s1p[jW][row] = v1; s2p[jW][row] = v2; }
            }
        }
        __syncthreads();  // (c) s1p/s2p ready
        if (tid < 64) {
            s1[(b * T_ + t) * C_ + tid] = s1p[0][tid] + s1p[1][tid];
            s2[(b * T_ + t) * C_ + tid] = s2p[0][tid] + s2p[1][tid];
        }
    }
    // block-end: quadrants disjoint -> direct atomicAdd
#pragma unroll
    for (int i2 = 0; i2 < 2; i2++)
#pragma unroll
        for (int j2 = 0; j2 < 2; j2++)
#pragma unroll
            for (int r = 0; r < 4; r++) {
                int row = (rt0 + i2) * 16 + quad * 4 + r;
                int col = (ct0 + j2) * 16 + l16;
                atomicAdd(&A[b * (C_ * C_) + row * C_ + col], accA[i2][j2][r]);
            }
}

// ---------------------------------------------------------------------------
// K2: top-4 selection + symmetrize -> amask bitmask per (b,c). grid B, block 64
// ---------------------------------------------------------------------------
__global__ __launch_bounds__(64) void k_topk(const float* __restrict__ A,
                                             unsigned long long* __restrict__ amask) {
    int b = blockIdx.x;
    int c = threadIdx.x;
    __shared__ unsigned long long tk[C_];
    const float* row = A + b * (C_ * C_) + c * C_;
    unsigned long long sel = 0ULL;
    for (int r = 0; r < 4; r++) {
        float best = -1e30f;
        int bi = 0;
        for (int d = 0; d < C_; d++) {
            if (sel & (1ULL << d)) continue;
            float v = row[d];
            if (v > best) { best = v; bi = d; }
        }
        sel |= (1ULL << bi);
    }
    unsigned long long t = sel & ~(1ULL << c);
    tk[c] = t;
    __syncthreads();
    unsigned long long sym = t;
    for (int d = 0; d < C_; d++)
        if ((tk[d] >> c) & 1ULL) sym |= (1ULL << d);
    unsigned long long m = (1ULL << c);
    unsigned long long s2 = sym;
    while (s2) {
        int d = __ffsll(s2) - 1;
        s2 &= s2 - 1;
        if (row[d] > 0.f) m |= (1ULL << d);
    }
    amask[b * C_ + c] = m;
}

// ---------------------------------------------------------------------------
// K3: GAT attention + relu + pooling. block 256 = 4 waves = 4 t's. grid B*T/4.
// ---------------------------------------------------------------------------
__global__ __launch_bounds__(256) void k_gat(
    const float* __restrict__ Wh, const float* __restrict__ s1,
    const float* __restrict__ s2, const unsigned long long* __restrict__ amask,
    const float* __restrict__ pool_w, const float* __restrict__ pool_b,
    float* __restrict__ hout) {
    int tg = blockIdx.x;
    int wv = threadIdx.x >> 6, c = threadIdx.x & 63;
    int bt = tg * 4 + wv;
    int b = bt >> 8;
    __shared__ float buf[4][C_][33];
    __shared__ float s2s[4][C_];

    s2s[wv][c] = s2[bt * C_ + c];
    float s1c = s1[bt * C_ + c];
    unsigned long long m = amask[b * C_ + c];
    __syncthreads();

    float mx = -1e30f;
    unsigned long long mm = m;
    while (mm) {
        int d = __ffsll(mm) - 1; mm &= mm - 1;
        float v = s1c + s2s[wv][d];
        v = v > 0.f ? v : 0.2f * v;
        mx = fmaxf(mx, v);
    }
    float ssum = 0.f;
    mm = m;
    while (mm) {
        int d = __ffsll(mm) - 1; mm &= mm - 1;
        float v = s1c + s2s[wv][d];
        v = v > 0.f ? v : 0.2f * v;
        ssum += __expf(v - mx);
    }
    float inv = 1.0f / ssum;
    float g[O_];
#pragma unroll
    for (int i = 0; i < O_; i++) g[i] = 0.f;
    mm = m;
    while (mm) {
        int d = __ffsll(mm) - 1; mm &= mm - 1;
        float v = s1c + s2s[wv][d];
        v = v > 0.f ? v : 0.2f * v;
        float a = __expf(v - mx);
        const float4* wr = (const float4*)(Wh + (size_t)bt * (C_ * O_) + d * O_);
#pragma unroll
        for (int q = 0; q < 8; q++) {
            float4 w4 = wr[q];
            g[4 * q + 0] += a * w4.x;
            g[4 * q + 1] += a * w4.y;
            g[4 * q + 2] += a * w4.z;
            g[4 * q + 3] += a * w4.w;
        }
    }
    float lg = pool_b[0];
#pragma unroll
    for (int i = 0; i < O_; i++) {
        g[i] = fmaxf(g[i] * inv, 0.f);
        lg += g[i] * pool_w[i];
    }
    float wmx = lg;
#pragma unroll
    for (int s = 1; s < 64; s <<= 1) wmx = fmaxf(wmx, __shfl_xor(wmx, s));
    float we = __expf(lg - wmx);
    float wsum = we;
#pragma unroll
    for (int s = 1; s < 64; s <<= 1) wsum += __shfl_xor(wsum, s);
    float wcf = we / wsum;
#pragma unroll
    for (int i = 0; i < O_; i++) buf[wv][c][i] = g[i] * wcf;
    __syncthreads();
    {
        int wt = threadIdx.x >> 6, o = threadIdx.x & 31, hf = (threadIdx.x >> 5) & 1;
        float sacc = 0.f;
#pragma unroll 8
        for (int d = hf * 32; d < hf * 32 + 32; d++) sacc += buf[wt][d][o];
        sacc += __shfl_xor(sacc, 32);
        if (hf == 0) hout[(tg * 4 + wt) * O_ + o] = sacc;
    }
}

// ---------------------------------------------------------------------------
// K4a: LSTM input projection gx = h @ Wi + b. grid 2*B*T, block 128
// ---------------------------------------------------------------------------
__global__ __launch_bounds__(128) void k_lstm_pre(
    const float* __restrict__ hin,
    const float* __restrict__ Wi_f, const float* __restrict__ b_f,
    const float* __restrict__ Wi_r, const float* __restrict__ b_r,
    float* __restrict__ gx) {
    int id = blockIdx.x;
    int dir = id >> 12;
    int bt = id & 4095;
    const float* Wi = dir ? Wi_r : Wi_f;
    const float* bb = dir ? b_r : b_f;
    int g = threadIdx.x;
    __shared__ float hs[H_];
    if (g < H_) hs[g] = hin[bt * O_ + g];
    __syncthreads();
    float acc = bb[g];
#pragma unroll
    for (int k = 0; k < H_; k++) acc += hs[k] * Wi[k * G4_ + g];
    gx[((size_t)dir * 4096 + bt) * G4_ + g] = acc;
}

// ---------------------------------------------------------------------------
// K4b: LSTM recurrence — single wave per (dir,b).
// amdgpu_waves_per_eu(1,1): pins occupancy target to 1 wave/EU so the
// scheduler/RA uses the full 512-VGPR budget instead of spilling the 64
// loop-invariant weights to scratch (R3/R4: VGPR_Count=40 despite
// __launch_bounds__(64,1) — 2nd arg is only a MIN, backend default already 1,
// so the occupancy heuristic still aimed high and spilled).
// ww_k = (W[k][lane], W[k][lane+64]):
//   lanes 0..31:  g0 = gate i, g1 = gate g
//   lanes 32..63: g0 = gate f, g1 = gate o
// grid 2*B, block 64.
// ---------------------------------------------------------------------------
#define WW(k) float2 ww##k = make_float2(Wd[(k) * G4_ + lane], Wd[(k) * G4_ + lane + 64]);
#define KST(k, Aq) { float hk = readlane_f(h, k); \
    Aq.x = fmaf(hk, ww##k.x, Aq.x); Aq.y = fmaf(hk, ww##k.y, Aq.y); }

__global__ void __attribute__((amdgpu_flat_work_group_size(64, 64)))
__attribute__((amdgpu_waves_per_eu(1, 1))) k_lstm_seq(
    const float* __restrict__ gx,
    const float* __restrict__ Whf, const float* __restrict__ Whr,
    float* __restrict__ hcat) {
    int dir = blockIdx.x & 1, b = blockIdx.x >> 1;
    int lane = threadIdx.x;
    const float* Wd = dir ? Whr : Whf;
    WW(0) WW(1) WW(2) WW(3) WW(4) WW(5) WW(6) WW(7)
    WW(8) WW(9) WW(10) WW(11) WW(12) WW(13) WW(14) WW(15)
    WW(16) WW(17) WW(18) WW(19) WW(20) WW(21) WW(22) WW(23)
    WW(24) WW(25) WW(26) WW(27) WW(28) WW(29) WW(30) WW(31)

    const float* gxb = gx + ((size_t)dir * 4096 + b * T_) * G4_;
    float h = 0.f, cst = 0.f;
    const int dt = dir ? -1 : 1;
    int t = dir ? (T_ - 1) : 0;
    float g0n = gxb[t * G4_ + lane], g1n = gxb[t * G4_ + lane + 64];
    const float half_sel = (lane < 32) ? 2.f : 1.f;
    for (int s = 0; s < T_; s++) {
        int tn = t + dt;
        float2 A0 = make_float2(g0n, g1n);
        float2 A1 = make_float2(0.f, 0.f);
        float2 A2 = make_float2(0.f, 0.f);
        float2 A3 = make_float2(0.f, 0.f);
        if (s < T_ - 1) {
            g0n = gxb[tn * G4_ + lane];
            g1n = gxb[tn * G4_ + lane + 64];
        }
        KST(0, A0)  KST(1, A1)  KST(2, A2)  KST(3, A3)
        KST(4, A0)  KST(5, A1)  KST(6, A2)  KST(7, A3)
        KST(8, A0)  KST(9, A1)  KST(10, A2) KST(11, A3)
        KST(12, A0) KST(13, A1) KST(14, A2) KST(15, A3)
        KST(16, A0) KST(17, A1) KST(18, A2) KST(19, A3)
        KST(20, A0) KST(21, A1) KST(22, A2) KST(23, A3)
        KST(24, A0) KST(25, A1) KST(26, A2) KST(27, A3)
        KST(28, A0) KST(29, A1) KST(30, A2) KST(31, A3)
        float g0 = (A0.x + A1.x) + (A2.x + A3.x);
        float g1 = (A0.y + A1.y) + (A2.y + A3.y);
        // lanes<32: sA=sigm(i), sB=tanh(g)=2*sigm(2g)-1 ; lanes>=32: sA=sigm(f), sB=sigm(o)
        float sA = sigm_f(g0);
        float u = sigm_f(half_sel * g1);
        float sB = (lane < 32) ? fmaf(2.f, u, -1.f) : u;
        float sf = __shfl(sA, (lane & 31) + 32);
        float so = __shfl(sB, (lane & 31) + 32);
        cst = fmaf(sf, cst, sA * sB);
        float hn = so * tanh_f(cst);
        h = hn;
        if (lane < H_) hcat[((size_t)(b * T_) + t) * (2 * H_) + dir * H_ + lane] = hn;
        t = tn;
    }
}

// ---------------------------------------------------------------------------
// K5: temporal attention + LN + fc1 + fc2 -> out (B,3). grid B, block 256.
// ---------------------------------------------------------------------------
__global__ __launch_bounds__(256) void k_final(
    const float* __restrict__ hcat,
    const float* __restrict__ taW, const float* __restrict__ tab,
    const float* __restrict__ tav,
    const float* __restrict__ lng, const float* __restrict__ lnb,
    const float* __restrict__ w1, const float* __restrict__ b1,
    const float* __restrict__ w2, const float* __restrict__ b2,
    float* __restrict__ out) {
    int b = blockIdx.x;
    int t = threadIdx.x;
    __shared__ float Wl[64 * 64];
    __shared__ float al[T_];
    __shared__ float wred[4];
    __shared__ float ctxp[4][64];
    __shared__ float ctx[64];
    __shared__ float a1[32];
    for (int i = t; i < 4096; i += 256) Wl[i] = taW[i];
    float4 hr[16];
    const float4* hb = (const float4*)(hcat + ((size_t)b * T_ + t) * 64);
#pragma unroll
    for (int i = 0; i < 16; i++) hr[i] = hb[i];
    __syncthreads();
    float sc = 0.f;
    for (int j = 0; j < 64; j++) {
        float s = tab[j];
#pragma unroll
        for (int k4 = 0; k4 < 16; k4++) {
            float4 h4 = hr[k4];
            const float* wcol = &Wl[(4 * k4) * 64 + j];
            s += h4.x * wcol[0] + h4.y * wcol[64] + h4.z * wcol[128] + h4.w * wcol[192];
        }
        sc += tanhf(s) * tav[j];
    }
    sc *= (1.0f / 1.5f);
    int wave = t >> 6, lane = t & 63;
    float m = sc;
#pragma unroll
    for (int s_ = 1; s_ < 64; s_ <<= 1) m = fmaxf(m, __shfl_xor(m, s_));
    if (lane == 0) wred[wave] = m;
    __syncthreads();
    m = fmaxf(fmaxf(wred[0], wred[1]), fmaxf(wred[2], wred[3]));
    float e = __expf(sc - m);
    float ssum = e;
#pragma unroll
    for (int s_ = 1; s_ < 64; s_ <<= 1) ssum += __shfl_xor(ssum, s_);
    __syncthreads();
    if (lane == 0) wred[wave] = ssum;
    __syncthreads();
    float S = wred[0] + wred[1] + wred[2] + wred[3];
    al[t] = e / S;
    __syncthreads();
    // ctx partials: thread = (part = t>>6, o = t&63)
    {
        int o = t & 63, part = t >> 6;
        float cacc = 0.f;
        for (int tt = part * 64; tt < part * 64 + 64; tt++)
            cacc += al[tt] * hcat[((size_t)b * T_ + tt) * 64 + o];
        ctxp[part][o] = cacc;
    }
    __syncthreads();
    if (t < 64) {
        float ctxo = ctxp[0][t] + ctxp[1][t] + ctxp[2][t] + ctxp[3][t];
        float sv = ctxo, sq = ctxo * ctxo;
#pragma unroll
        for (int s_ = 1; s_ < 64; s_ <<= 1) {
            sv += __shfl_xor(sv, s_);
            sq += __shfl_xor(sq, s_);
        }
        float mu = sv * (1.f / 64.f);
        float var = sq * (1.f / 64.f) - mu * mu;
        ctx[t] = (ctxo - mu) / sqrtf(var + 1e-5f) * lng[t] + lnb[t];
    }
    __syncthreads();
    if (t < 32) {
        float s = b1[t];
        for (int k = 0; k < 64; k++) s += ctx[k] * w1[k * 32 + t];
        a1[t] = fmaxf(s, 0.f);
    }
    __syncthreads();
    if (t < 3) {
        float s = b2[t];
        for (int k = 0; k < 32; k++) s += a1[k] * w2[k * 3 + t];
        out[b * 3 + t] = s;
    }
}

// ---------------------------------------------------------------------------
extern "C" void kernel_launch(void* const* d_in, const int* in_sizes, int n_in,
                              void* d_out, int out_size, void* d_ws, size_t ws_size,
                              hipStream_t stream) {
    const float* x          = (const float*)d_in[0];
    const float* spectral_w = (const float*)d_in[1];
    const float* gat_W      = (const float*)d_in[2];
    const float* gat_a      = (const float*)d_in[3];
    const float* pool_w     = (const float*)d_in[4];
    const float* pool_b     = (const float*)d_in[5];
    const float* lstm_Wi_f  = (const float*)d_in[6];
    const float* lstm_Wh_f  = (const float*)d_in[7];
    const float* lstm_b_f   = (const float*)d_in[8];
    const float* lstm_Wi_r  = (const float*)d_in[9];
    const float* lstm_Wh_r  = (const float*)d_in[10];
    const float* lstm_b_r   = (const float*)d_in[11];
    const float* ta_W       = (const float*)d_in[12];
    const float* ta_b       = (const float*)d_in[13];
    const float* ta_v       = (const float*)d_in[14];
    const float* ln_g       = (const float*)d_in[15];
    const float* ln_b       = (const float*)d_in[16];
    const float* fc1_w      = (const float*)d_in[17];
    const float* fc1_b      = (const float*)d_in[18];
    const float* fc2_w      = (const float*)d_in[19];
    const float* fc2_b      = (const float*)d_in[20];
    float* out = (float*)d_out;

    float* ws = (float*)d_ws;
    float* sw    = ws + 0;                         // 8192
    float* A     = ws + 8192;                      // 65536
    unsigned long long* amask = (unsigned long long*)(ws + 73728);  // 1024 u64
    float* Wh    = ws + 75776;                     // 8388608
    float* s1    = ws + 8464384;                   // 262144
    float* s2    = ws + 8726528;                   // 262144
    float* hpool = ws + 8988672;                   // 131072
    float* gx    = ws + 9119744;                   // 1048576
    float* hcat  = ws + 10168320;                  // 262144

    hipMemsetAsync(A, 0, (size_t)C_ * C_ * B_ * sizeof(float), stream);
    k_sw<<<C_, 64, 0, stream>>>(spectral_w, sw);
    k_phase1<<<dim3(B_, T_ / TCP), 256, 0, stream>>>(x, sw, gat_W, gat_a, A, Wh, s1, s2);
    k_topk<<<B_, 64, 0, stream>>>(A, amask);
    k_gat<<<B_ * T_ / 4, 256, 0, stream>>>(Wh, s1, s2, amask, pool_w, pool_b, hpool);
    k_lstm_pre<<<2 * B_ * T_, 128, 0, stream>>>(hpool, lstm_Wi_f, lstm_b_f,
                                                lstm_Wi_r, lstm_b_r, gx);
    k_lstm_seq<<<2 * B_, 64, 0, stream>>>(gx, lstm_Wh_f, lstm_Wh_r, hcat);
    k_final<<<B_, 256, 0, stream>>>(hcat, ta_W, ta_b, ta_v, ln_g, ln_b,
                                    fc1_w, fc1_b, fc2_w, fc2_b, out);
}